// Round 4
// baseline (413.788 us; speedup 1.0000x reference)
//
#include <hip/hip_runtime.h>
#include <math.h>

// B=512, IN_CORES=12, N_PRIM=12, N_PAR=10, RFPC=4, RF=64, CAP=256
// out = concat( sigmoid MLP output (512,3072) f32 , x_sum (512,2560) f32 )
//
// R4 changes vs R3 (392 us):
//  1. gemm_splitk_f / gemm_l1_f: 2-phase double-buffered K-loop (T3-minimum):
//     issue next tile's global_load_lds BEFORE compute of current tile, one
//     barrier per step. R3 did STAGE->barrier(drain)->compute: zero overlap.
//  2. conv_guest v2: LDS-free transpose. Thread reads 16 strided scalars
//     (4x64B coalesced segments/inst, 16 loads in flight), packs bf16 in
//     regs, one 32B store. No LDS, no barrier (was the 2.1 TB/s ceiling).
//  3. mask/bucket/combine kernels: dead LDS removed (guests need none).

#define BATCH 512
#define OUT0_SZ (512*3072)

#define KP1 2576     // Wt1 row stride (bf16), 5152 B
#define KP2 5136     // Wt2 row stride, 10272 B
#define KP3 4112     // Wt3 row stride, 8224 B
#define LD_XREC 2576
#define LD_H1 5136
#define LD_H2 4112
#define LDP2 4224    // Pbuf f32 stride for L2 (16896 B)
#define LDP3 3200    // Pbuf f32 stride for L3 (12800 B)
#define SPLITK 4

typedef __attribute__((ext_vector_type(8))) short short8;   // 8 x bf16
typedef __attribute__((ext_vector_type(4))) float f32x4;

__device__ inline unsigned short f2bf(float f) {
    union { float f; unsigned u; } v; v.f = f;
    unsigned r = v.u + 0x7fffu + ((v.u >> 16) & 1u);   // RNE
    return (unsigned short)(r >> 16);
}
__device__ inline float bf2f(unsigned int hi16) {
    union { unsigned u; float f; } v; v.u = hi16 << 16; return v.f;
}

#define GLD16(g, l) __builtin_amdgcn_global_load_lds( \
    (const __attribute__((address_space(1))) unsigned int*)(g), \
    (__attribute__((address_space(3))) unsigned int*)(l), 16, 0, 0)

#define CONV_PARAMS const float* __restrict__ cWr1, unsigned short* __restrict__ cWt1, \
    const float* __restrict__ cWr2, unsigned short* __restrict__ cWt2, \
    const float* __restrict__ cWr3, unsigned short* __restrict__ cWt3

// ---------------------------------------------------------------------------
// Guest v2: one 64x64 transpose tile, LDS-free.
// Thread -> output row nr = tid>>2, k-chunk kc = (tid&3)*16.
// Load i: lanes {c + 4j} (fixed c) read 16 consecutive n at one k-row ->
// 4 x 64B coalesced segments per instruction; 16 loads in flight/thread.
// Tile index space: [0,3200) Wt1 | [3200,8320) Wt2 | [8320,11392) Wt3.
// ---------------------------------------------------------------------------
__device__ void conv_guest(int t, CONV_PARAMS)
{
    const float* W; unsigned short* Wt;
    int Kr, Nr, Kp, ktiles, rem;
    if (t < 3200)      { W = cWr1; Wt = cWt1; Kr = 2560; Nr = 5000; Kp = KP1; ktiles = 40; rem = t; }
    else if (t < 8320) { W = cWr2; Wt = cWt2; Kr = 5000; Nr = 4000; Kp = KP2; ktiles = 80; rem = t - 3200; }
    else               { W = cWr3; Wt = cWt3; Kr = 4000; Nr = 3072; Kp = KP3; ktiles = 64; rem = t - 8320; }
    int k0 = (rem % ktiles) * 64;
    int n0 = (rem / ktiles) * 64;
    int tid = threadIdx.x;

    int nr = tid >> 2;           // output row within tile (0..63)
    int kc = (tid & 3) * 16;     // k chunk (0,16,32,48)
    int n = n0 + nr;

    float v[16];
    if (n < Nr) {
        const float* col = W + (size_t)(k0 + kc) * Nr + n;
        #pragma unroll
        for (int i = 0; i < 16; ++i) {
            int k = k0 + kc + i;
            v[i] = (k < Kr) ? col[(size_t)i * Nr] : 0.f;
        }
    } else {
        #pragma unroll
        for (int i = 0; i < 16; ++i) v[i] = 0.f;
    }
    unsigned int u[8];
    #pragma unroll
    for (int j = 0; j < 8; ++j)
        u[j] = (unsigned int)f2bf(v[2 * j]) | ((unsigned int)f2bf(v[2 * j + 1]) << 16);
    unsigned int* dst = (unsigned int*)&Wt[(size_t)n * Kp + k0 + kc];
    *(uint4*)(dst)     = make_uint4(u[0], u[1], u[2], u[3]);
    *(uint4*)(dst + 4) = make_uint4(u[4], u[5], u[6], u[7]);
}

// ---------------------------------------------------------------------------
// Small standalone: capsule weight transposes W1 (48) + W2 (40), 64x64 each.
// ---------------------------------------------------------------------------
__global__ __launch_bounds__(256) void conv_small(
    const float* __restrict__ W1, unsigned short* __restrict__ W1t,
    const float* __restrict__ W2, unsigned short* __restrict__ W2t)
{
    int bid = blockIdx.x;
    const float* W; unsigned short* Wt;
    if (bid < 48) { W = W1 + (size_t)bid * 4096; Wt = W1t + (size_t)bid * 4096; }
    else          { W = W2 + (size_t)(bid - 48) * 4096; Wt = W2t + (size_t)(bid - 48) * 4096; }
    int tid = threadIdx.x;
    int nr = tid >> 2;
    int kc = (tid & 3) * 16;
    float v[16];
    #pragma unroll
    for (int i = 0; i < 16; ++i)
        v[i] = W[(size_t)(kc + i) * 64 + nr];
    unsigned int u[8];
    #pragma unroll
    for (int j = 0; j < 8; ++j)
        u[j] = (unsigned int)f2bf(v[2 * j]) | ((unsigned int)f2bf(v[2 * j + 1]) << 16);
    unsigned int* dst = (unsigned int*)&Wt[(size_t)nr * 64 + kc];
    *(uint4*)(dst)     = make_uint4(u[0], u[1], u[2], u[3]);
    *(uint4*)(dst + 4) = make_uint4(u[4], u[5], u[6], u[7]);
}

// ---------------------------------------------------------------------------
// Capsule layer 1 (host 192 blocks) + conv guests.
// ---------------------------------------------------------------------------
__global__ __launch_bounds__(256) void caps_gemm1_f(
    const float* __restrict__ x, const float* __restrict__ C1,
    const unsigned short* __restrict__ W1t, const float* __restrict__ b1,
    unsigned short* __restrict__ xp, int hostBlocks, int guestBase,
    CONV_PARAMS)
{
    if ((int)blockIdx.x >= hostBlocks) {
        conv_guest(guestBase + blockIdx.x - hostBlocks, cWr1, cWt1, cWr2, cWt2, cWr3, cWt3);
        return;
    }
    __shared__ __align__(16) char smem[27840];
    unsigned short* As = (unsigned short*)smem;            // 128*72
    unsigned short* Bs = (unsigned short*)(smem + 18432);  // 64*72
    float* Csh = (float*)(smem + 27648);                   // 48

    int kl = blockIdx.x % 48;
    int bm = (blockIdx.x / 48) * 128;
    int tid = threadIdx.x;
    int w = tid >> 6, lane = tid & 63, q = lane >> 4, r16 = lane & 15;
    int wm = (w >> 1) * 64, wn = (w & 1) * 32;

    if (tid < 48) Csh[tid] = C1[tid * 48 + kl];
    {
        const uint4* src = (const uint4*)(W1t + (size_t)kl * 4096);
        #pragma unroll
        for (int p = 0; p < 2; ++p) {
            int c = tid + p * 256;
            int row = c >> 3, cq = c & 7;
            *(uint4*)&Bs[row * 72 + cq * 8] = src[c];
        }
    }
    __syncthreads();

    int arow = tid >> 1, ah = (tid & 1) * 32;
    float accp[32];
    #pragma unroll
    for (int i = 0; i < 32; ++i) accp[i] = 0.f;
    const float* xrow = x + (size_t)(bm + arow) * 3072 + ah;
    for (int ij = 0; ij < 48; ++ij) {
        float c = Csh[ij];
        if (c != 0.f) {
            const float4* p4 = (const float4*)(xrow + ij * 64);
            #pragma unroll
            for (int cc = 0; cc < 8; ++cc) {
                float4 v = p4[cc];
                accp[cc * 4 + 0] = fmaf(c, v.x, accp[cc * 4 + 0]);
                accp[cc * 4 + 1] = fmaf(c, v.y, accp[cc * 4 + 1]);
                accp[cc * 4 + 2] = fmaf(c, v.z, accp[cc * 4 + 2]);
                accp[cc * 4 + 3] = fmaf(c, v.w, accp[cc * 4 + 3]);
            }
        }
    }
    {
        unsigned short* dst = &As[arow * 72 + ah];
        #pragma unroll
        for (int cc = 0; cc < 4; ++cc) {
            unsigned int u[4];
            #pragma unroll
            for (int j = 0; j < 4; ++j)
                u[j] = (unsigned int)f2bf(accp[cc * 8 + 2 * j]) |
                       ((unsigned int)f2bf(accp[cc * 8 + 2 * j + 1]) << 16);
            *(uint4*)&dst[cc * 8] = make_uint4(u[0], u[1], u[2], u[3]);
        }
    }
    __syncthreads();

    f32x4 acc[4][2];
    #pragma unroll
    for (int i = 0; i < 4; ++i)
        #pragma unroll
        for (int j = 0; j < 2; ++j) acc[i][j] = (f32x4)0.f;
    #pragma unroll
    for (int ks = 0; ks < 2; ++ks) {
        short8 a[4], b[2];
        #pragma unroll
        for (int mt = 0; mt < 4; ++mt)
            a[mt] = *(const short8*)&As[(wm + mt * 16 + r16) * 72 + ks * 32 + q * 8];
        #pragma unroll
        for (int nt = 0; nt < 2; ++nt)
            b[nt] = *(const short8*)&Bs[(wn + nt * 16 + r16) * 72 + ks * 32 + q * 8];
        #pragma unroll
        for (int mt = 0; mt < 4; ++mt)
            #pragma unroll
            for (int nt = 0; nt < 2; ++nt)
                acc[mt][nt] = __builtin_amdgcn_mfma_f32_16x16x32_bf16(a[mt], b[nt], acc[mt][nt], 0, 0, 0);
    }

    #pragma unroll
    for (int mt = 0; mt < 4; ++mt) {
        #pragma unroll
        for (int nt = 0; nt < 2; ++nt) {
            int n = wn + nt * 16 + r16;
            float bv = b1[kl * 64 + n];
            #pragma unroll
            for (int reg = 0; reg < 4; ++reg) {
                int row = bm + wm + mt * 16 + q * 4 + reg;
                xp[(size_t)row * 3072 + kl * 64 + n] = f2bf(fmaxf(acc[mt][nt][reg] + bv, 0.f));
            }
        }
    }
}

// ---------------------------------------------------------------------------
// Capsule layer 2 + skip + norms (host 160 blocks) + conv guests.
// ---------------------------------------------------------------------------
__global__ __launch_bounds__(256) void caps_gemm2_f(
    const unsigned short* __restrict__ xp, const float* __restrict__ Cs,
    const float* __restrict__ C2, const unsigned short* __restrict__ W2t,
    const float* __restrict__ b2, float* __restrict__ xsum,
    float* __restrict__ part8, int hostBlocks, int guestBase,
    CONV_PARAMS)
{
    if ((int)blockIdx.x >= hostBlocks) {
        conv_guest(guestBase + blockIdx.x - hostBlocks, cWr1, cWt1, cWr2, cWt2, cWr3, cWt3);
        return;
    }
    __shared__ __align__(16) char smem[28032];
    unsigned short* As = (unsigned short*)smem;
    unsigned short* Bs = (unsigned short*)(smem + 18432);
    float* C2sh = (float*)(smem + 27648);
    float* Cssh = (float*)(smem + 27840);

    int kl = blockIdx.x % 40;
    int bm = (blockIdx.x / 40) * 128;
    int tid = threadIdx.x;
    int w = tid >> 6, lane = tid & 63, q = lane >> 4, r16 = lane & 15;
    int wm = (w >> 1) * 64, wn = (w & 1) * 32;
    int half = w & 1;

    if (tid < 48) { C2sh[tid] = C2[tid * 40 + kl]; Cssh[tid] = Cs[tid * 40 + kl]; }
    {
        const uint4* src = (const uint4*)(W2t + (size_t)kl * 4096);
        #pragma unroll
        for (int p = 0; p < 2; ++p) {
            int c = tid + p * 256;
            int row = c >> 3, cq = c & 7;
            *(uint4*)&Bs[row * 72 + cq * 8] = src[c];
        }
    }
    __syncthreads();

    int arow = tid >> 1, ah = (tid & 1) * 32;
    float accp[32], skp[32];
    #pragma unroll
    for (int i = 0; i < 32; ++i) { accp[i] = 0.f; skp[i] = 0.f; }
    const unsigned short* xprow = xp + (size_t)(bm + arow) * 3072 + ah;
    for (int ij = 0; ij < 48; ++ij) {
        float c2 = C2sh[ij], cs = Cssh[ij];
        if (c2 != 0.f || cs != 0.f) {
            const uint4* p4 = (const uint4*)(xprow + ij * 64);
            #pragma unroll
            for (int cc = 0; cc < 4; ++cc) {
                uint4 v = p4[cc];
                unsigned int uu[4] = {v.x, v.y, v.z, v.w};
                #pragma unroll
                for (int j = 0; j < 4; ++j) {
                    float lo = bf2f(uu[j] & 0xffffu);
                    float hi = bf2f(uu[j] >> 16);
                    int idx = cc * 8 + 2 * j;
                    accp[idx]     = fmaf(c2, lo, accp[idx]);
                    accp[idx + 1] = fmaf(c2, hi, accp[idx + 1]);
                    skp[idx]      = fmaf(cs, lo, skp[idx]);
                    skp[idx + 1]  = fmaf(cs, hi, skp[idx + 1]);
                }
            }
        }
    }
    {
        unsigned short* dst = &As[arow * 72 + ah];
        #pragma unroll
        for (int cc = 0; cc < 4; ++cc) {
            unsigned int u[4];
            #pragma unroll
            for (int j = 0; j < 4; ++j)
                u[j] = (unsigned int)f2bf(accp[cc * 8 + 2 * j]) |
                       ((unsigned int)f2bf(accp[cc * 8 + 2 * j + 1]) << 16);
            *(uint4*)&dst[cc * 8] = make_uint4(u[0], u[1], u[2], u[3]);
        }
        // skip -> global xsum (read back by epilogue after barrier)
        float* sx = xsum + (size_t)(bm + arow) * 2560 + kl * 64 + ah;
        #pragma unroll
        for (int cc = 0; cc < 8; ++cc)
            *(float4*)&sx[cc * 4] = make_float4(skp[cc*4], skp[cc*4+1], skp[cc*4+2], skp[cc*4+3]);
    }
    __syncthreads();

    f32x4 acc[4][2];
    #pragma unroll
    for (int i = 0; i < 4; ++i)
        #pragma unroll
        for (int j = 0; j < 2; ++j) acc[i][j] = (f32x4)0.f;
    #pragma unroll
    for (int ks = 0; ks < 2; ++ks) {
        short8 a[4], b[2];
        #pragma unroll
        for (int mt = 0; mt < 4; ++mt)
            a[mt] = *(const short8*)&As[(wm + mt * 16 + r16) * 72 + ks * 32 + q * 8];
        #pragma unroll
        for (int nt = 0; nt < 2; ++nt)
            b[nt] = *(const short8*)&Bs[(wn + nt * 16 + r16) * 72 + ks * 32 + q * 8];
        #pragma unroll
        for (int mt = 0; mt < 4; ++mt)
            #pragma unroll
            for (int nt = 0; nt < 2; ++nt)
                acc[mt][nt] = __builtin_amdgcn_mfma_f32_16x16x32_bf16(a[mt], b[nt], acc[mt][nt], 0, 0, 0);
    }

    #pragma unroll
    for (int mt = 0; mt < 4; ++mt) {
        float sreg[4] = {0.f, 0.f, 0.f, 0.f};
        #pragma unroll
        for (int nt = 0; nt < 2; ++nt) {
            int n = wn + nt * 16 + r16;
            float bv = b2[kl * 64 + n];
            #pragma unroll
            for (int reg = 0; reg < 4; ++reg) {
                int lr = wm + mt * 16 + q * 4 + reg;
                size_t xi = (size_t)(bm + lr) * 2560 + kl * 64 + n;
                float v = xsum[xi] + fmaxf(acc[mt][nt][reg] + bv, 0.f);
                xsum[xi] = v;
                sreg[reg] += v * v;
            }
        }
        #pragma unroll
        for (int reg = 0; reg < 4; ++reg) {
            float s = sreg[reg];
            s += __shfl_xor(s, 1); s += __shfl_xor(s, 2);
            s += __shfl_xor(s, 4); s += __shfl_xor(s, 8);
            if (r16 == 0) {
                int row = bm + wm + mt * 16 + q * 4 + reg;
                part8[(size_t)row * 80 + kl * 2 + half] = s;
            }
        }
    }
}

// ---------------------------------------------------------------------------
// Norm-argmax (host 512 blocks) + conv guests. Writes only active slice.
// ---------------------------------------------------------------------------
__global__ __launch_bounds__(256) void mask_f(
    const float* __restrict__ xs, const float* __restrict__ part8,
    unsigned short* __restrict__ xrec, int* __restrict__ active,
    int hostBlocks, int guestBase, CONV_PARAMS)
{
    if ((int)blockIdx.x >= hostBlocks) {
        conv_guest(guestBase + blockIdx.x - hostBlocks, cWr1, cWt1, cWr2, cWt2, cWr3, cWt3);
        return;
    }
    __shared__ float norms[10];
    __shared__ int act_sh;
    int b = blockIdx.x;
    int tid = threadIdx.x;
    if (tid < 10) {
        float s = 0.f;
        #pragma unroll
        for (int j = 0; j < 8; ++j) s += part8[(size_t)b * 80 + tid * 8 + j];
        norms[tid] = s;
    }
    __syncthreads();
    if (tid == 0) {
        int best = 0; float bn = -1.f;
        #pragma unroll
        for (int k = 0; k < 10; ++k)
            if (norms[k] > bn) { bn = norms[k]; best = k; }
        act_sh = best;
        active[b] = best;
    }
    __syncthreads();
    int act = act_sh;
    int idx = act * 256 + tid;
    xrec[(size_t)b * LD_XREC + idx] = f2bf(xs[(size_t)b * 2560 + idx]);
}

// ---------------------------------------------------------------------------
// Bucket rows by active capsule (host 1 block, 256 thr x 2 rows) + guests.
// ---------------------------------------------------------------------------
__global__ __launch_bounds__(256) void bucket_f(
    const int* __restrict__ active, int* __restrict__ perm,
    int4* __restrict__ slots, int hostBlocks, int guestBase, CONV_PARAMS)
{
    if ((int)blockIdx.x >= hostBlocks) {
        conv_guest(guestBase + blockIdx.x - hostBlocks, cWr1, cWt1, cWr2, cWt2, cWr3, cWt3);
        return;
    }
    __shared__ int cnt[10], pos[10];
    int tid = threadIdx.x;
    if (tid < 10) cnt[tid] = 0;
    __syncthreads();
    int a0 = active[tid], a1 = active[tid + 256];
    atomicAdd(&cnt[a0], 1);
    atomicAdd(&cnt[a1], 1);
    __syncthreads();
    if (tid == 0) {
        int o = 0, s = 0;
        for (int g = 0; g < 10; ++g) {
            pos[g] = o;
            int mg = cnt[g];
            for (int t0 = 0; t0 < mg; t0 += 64)
                slots[s++] = make_int4(g, o + t0, min(64, mg - t0), 0);
            o += mg;
        }
        for (; s < 18; ++s) slots[s] = make_int4(0, 0, 0, 0);
    }
    __syncthreads();
    int r0 = atomicAdd(&pos[a0], 1);
    perm[r0] = tid;
    int r1 = atomicAdd(&pos[a1], 1);
    perm[r1] = tid + 256;
}

// ---------------------------------------------------------------------------
// Grouped MLP layer-1 GEMM (host 40x18=720 blocks) + conv guests.
// 2-phase double-buffered K-loop (K=256, BK=32).
// ---------------------------------------------------------------------------
__global__ __launch_bounds__(256) void gemm_l1_f(
    const unsigned short* __restrict__ xrec, const int* __restrict__ perm,
    const int4* __restrict__ slots, const unsigned short* __restrict__ Wt1,
    const float* __restrict__ br1, unsigned short* __restrict__ h1,
    int hostBlocks, int guestBase, CONV_PARAMS)
{
    if ((int)blockIdx.x >= hostBlocks) {
        conv_guest(guestBase + blockIdx.x - hostBlocks, cWr1, cWt1, cWr2, cWt2, cWr3, cWt3);
        return;
    }
    __shared__ __align__(16) unsigned short As[2][64 * 32];
    __shared__ __align__(16) unsigned short Bs[2][128 * 32];
    __shared__ int rows[64];

    int sy = blockIdx.x % 18;
    int bn = (blockIdx.x / 18) * 128;
    int4 s = slots[sy];
    if (s.z == 0) return;
    int g = s.x, mstart = s.y, mval = s.z;
    int tid = threadIdx.x;

    if (tid < 64) rows[tid] = perm[mstart + min(tid, mval - 1)];
    __syncthreads();

    int w = tid >> 6, lane = tid & 63;
    int wm = (w >> 1) * 32, wn = (w & 1) * 64;
    int q = lane >> 4, r16 = lane & 15;
    int srow = tid >> 2, skq = tid & 3;

    f32x4 acc[2][4];
    #pragma unroll
    for (int i = 0; i < 2; ++i)
        #pragma unroll
        for (int j = 0; j < 4; ++j) acc[i][j] = (f32x4)0.f;

    int arow = rows[srow];
    const unsigned short* ga = xrec + (size_t)arow * LD_XREC + g * 256 + skq * 8;
    const unsigned short* gb = Wt1 + (size_t)(bn + srow) * KP1 + g * 256 + skq * 8;
    const unsigned short* gb2 = gb + (size_t)64 * KP1;

    // prologue: stage buf 0
    GLD16(ga, &As[0][tid * 8]);
    GLD16(gb, &Bs[0][tid * 8]);
    GLD16(gb2, &Bs[0][(tid + 256) * 8]);
    __syncthreads();

    int cur = 0;
    #pragma unroll 1
    for (int kk = 32; kk < 256; kk += 32) {
        int nxt = cur ^ 1;
        GLD16(ga + kk, &As[nxt][tid * 8]);
        GLD16(gb + kk, &Bs[nxt][tid * 8]);
        GLD16(gb2 + kk, &Bs[nxt][(tid + 256) * 8]);

        short8 a[2], b[4];
        #pragma unroll
        for (int mt = 0; mt < 2; ++mt)
            a[mt] = *(const short8*)&As[cur][(wm + mt * 16 + r16) * 32 + q * 8];
        #pragma unroll
        for (int nt = 0; nt < 4; ++nt)
            b[nt] = *(const short8*)&Bs[cur][(wn + nt * 16 + r16) * 32 + q * 8];
        #pragma unroll
        for (int mt = 0; mt < 2; ++mt)
            #pragma unroll
            for (int nt = 0; nt < 4; ++nt)
                acc[mt][nt] = __builtin_amdgcn_mfma_f32_16x16x32_bf16(a[mt], b[nt], acc[mt][nt], 0, 0, 0);
        __syncthreads();
        cur = nxt;
    }
    {   // final tile
        short8 a[2], b[4];
        #pragma unroll
        for (int mt = 0; mt < 2; ++mt)
            a[mt] = *(const short8*)&As[cur][(wm + mt * 16 + r16) * 32 + q * 8];
        #pragma unroll
        for (int nt = 0; nt < 4; ++nt)
            b[nt] = *(const short8*)&Bs[cur][(wn + nt * 16 + r16) * 32 + q * 8];
        #pragma unroll
        for (int mt = 0; mt < 2; ++mt)
            #pragma unroll
            for (int nt = 0; nt < 4; ++nt)
                acc[mt][nt] = __builtin_amdgcn_mfma_f32_16x16x32_bf16(a[mt], b[nt], acc[mt][nt], 0, 0, 0);
    }

    #pragma unroll
    for (int mt = 0; mt < 2; ++mt) {
        #pragma unroll
        for (int nt = 0; nt < 4; ++nt) {
            int n = bn + wn + nt * 16 + r16;
            float bv = (n < 5000) ? br1[n] : 0.f;
            #pragma unroll
            for (int reg = 0; reg < 4; ++reg) {
                int lm = wm + mt * 16 + q * 4 + reg;
                if (lm < mval)
                    h1[(size_t)(mstart + lm) * LD_H1 + n] =
                        f2bf(fmaxf(acc[mt][nt][reg] + bv, 0.f));
            }
        }
    }
}

// ---------------------------------------------------------------------------
// Split-K MFMA GEMM (64x128 tile, BK=32), 2-phase double-buffered K-loop,
// + optional conv guests. bid -> (x = bid%nbx, y = (bid/nbx)%8, z = rest).
// ---------------------------------------------------------------------------
__global__ __launch_bounds__(256) void gemm_splitk_f(
    const unsigned short* __restrict__ A, int ldA,
    const unsigned short* __restrict__ Bt, int ldB,
    float* __restrict__ P, int ldP, int Np, int kper, int nbx,
    int hostBlocks, int guestBase, CONV_PARAMS)
{
    if ((int)blockIdx.x >= hostBlocks) {
        conv_guest(guestBase + blockIdx.x - hostBlocks, cWr1, cWt1, cWr2, cWt2, cWr3, cWt3);
        return;
    }
    __shared__ __align__(16) unsigned short As[2][64 * 32];
    __shared__ __align__(16) unsigned short Bs[2][128 * 32];

    int tid = threadIdx.x;
    int bid = blockIdx.x;
    int bn = (bid % nbx) * 128;
    int bm = ((bid / nbx) & 7) * 64;
    int z  = bid / (nbx * 8);
    int kz = z * kper;

    int w = tid >> 6, lane = tid & 63;
    int wm = (w >> 1) * 32, wn = (w & 1) * 64;
    int q = lane >> 4, r16 = lane & 15;
    int srow = tid >> 2, skq = tid & 3;

    f32x4 acc[2][4];
    #pragma unroll
    for (int i = 0; i < 2; ++i)
        #pragma unroll
        for (int j = 0; j < 4; ++j) acc[i][j] = (f32x4)0.f;

    const unsigned short* ga  = A + (size_t)(bm + srow) * ldA + kz + skq * 8;
    const unsigned short* gb  = Bt + (size_t)(bn + srow) * ldB + kz + skq * 8;
    const unsigned short* gb2 = gb + (size_t)64 * ldB;

    // prologue: stage buf 0
    GLD16(ga, &As[0][tid * 8]);
    GLD16(gb, &Bs[0][tid * 8]);
    GLD16(gb2, &Bs[0][(tid + 256) * 8]);
    __syncthreads();

    int cur = 0;
    #pragma unroll 1
    for (int kk = 32; kk < kper; kk += 32) {
        int nxt = cur ^ 1;
        GLD16(ga + kk, &As[nxt][tid * 8]);
        GLD16(gb + kk, &Bs[nxt][tid * 8]);
        GLD16(gb2 + kk, &Bs[nxt][(tid + 256) * 8]);

        short8 a[2], b[4];
        #pragma unroll
        for (int mt = 0; mt < 2; ++mt)
            a[mt] = *(const short8*)&As[cur][(wm + mt * 16 + r16) * 32 + q * 8];
        #pragma unroll
        for (int nt = 0; nt < 4; ++nt)
            b[nt] = *(const short8*)&Bs[cur][(wn + nt * 16 + r16) * 32 + q * 8];
        #pragma unroll
        for (int mt = 0; mt < 2; ++mt)
            #pragma unroll
            for (int nt = 0; nt < 4; ++nt)
                acc[mt][nt] = __builtin_amdgcn_mfma_f32_16x16x32_bf16(a[mt], b[nt], acc[mt][nt], 0, 0, 0);
        __syncthreads();
        cur = nxt;
    }
    {   // final tile
        short8 a[2], b[4];
        #pragma unroll
        for (int mt = 0; mt < 2; ++mt)
            a[mt] = *(const short8*)&As[cur][(wm + mt * 16 + r16) * 32 + q * 8];
        #pragma unroll
        for (int nt = 0; nt < 4; ++nt)
            b[nt] = *(const short8*)&Bs[cur][(wn + nt * 16 + r16) * 32 + q * 8];
        #pragma unroll
        for (int mt = 0; mt < 2; ++mt)
            #pragma unroll
            for (int nt = 0; nt < 4; ++nt)
                acc[mt][nt] = __builtin_amdgcn_mfma_f32_16x16x32_bf16(a[mt], b[nt], acc[mt][nt], 0, 0, 0);
    }

    float* Pz = P + (size_t)z * 512 * ldP;
    #pragma unroll
    for (int mt = 0; mt < 2; ++mt) {
        #pragma unroll
        for (int nt = 0; nt < 4; ++nt) {
            int cn = bn + wn + nt * 16 + r16;
            #pragma unroll
            for (int reg = 0; reg < 4; ++reg) {
                int cm = bm + wm + mt * 16 + q * 4 + reg;
                Pz[(size_t)cm * ldP + cn] = acc[mt][nt][reg];
            }
        }
    }
}

// ---------------------------------------------------------------------------
// Combine split-K + bias + act (+ optional conv guests).
// MODE 0: relu->bf16 (stride ldO). MODE 1: sigmoid->f32, un-permute rows.
// ---------------------------------------------------------------------------
template<int MODE>
__global__ __launch_bounds__(256) void combine_f(
    const float* __restrict__ P, int ldP, const float* __restrict__ bias,
    void* __restrict__ out, int ldO, int Np, int N_real,
    const int* __restrict__ perm, int hostBlocks, int guestBase, CONV_PARAMS)
{
    if ((int)blockIdx.x >= hostBlocks) {
        conv_guest(guestBase + blockIdx.x - hostBlocks, cWr1, cWt1, cWr2, cWt2, cWr3, cWt3);
        return;
    }
    int gid = blockIdx.x * 256 + threadIdx.x;
    int n0 = (gid * 4) % Np;
    int m  = (gid * 4) / Np;
    size_t MN = (size_t)512 * ldP;
    const float* p = P + (size_t)m * ldP + n0;
    f32x4 s = *(const f32x4*)p;
    s += *(const f32x4*)(p + MN);
    s += *(const f32x4*)(p + 2 * MN);
    s += *(const f32x4*)(p + 3 * MN);
    f32x4 bv = (n0 < N_real) ? *(const f32x4*)(bias + n0) : (f32x4)0.f;
    s += bv;
    if (MODE == 0) {
        unsigned int lo = (unsigned int)f2bf(fmaxf(s[0], 0.f)) | ((unsigned int)f2bf(fmaxf(s[1], 0.f)) << 16);
        unsigned int hi = (unsigned int)f2bf(fmaxf(s[2], 0.f)) | ((unsigned int)f2bf(fmaxf(s[3], 0.f)) << 16);
        *(uint2*)((unsigned short*)out + (size_t)m * ldO + n0) = make_uint2(lo, hi);
    } else {
        int row = perm[m];
        f32x4 v;
        v[0] = 1.f / (1.f + expf(-s[0]));
        v[1] = 1.f / (1.f + expf(-s[1]));
        v[2] = 1.f / (1.f + expf(-s[2]));
        v[3] = 1.f / (1.f + expf(-s[3]));
        *(f32x4*)((float*)out + (size_t)row * ldO + n0) = v;
    }
}

extern "C" void kernel_launch(void* const* d_in, const int* in_sizes, int n_in,
                              void* d_out, int out_size, void* d_ws, size_t ws_size,
                              hipStream_t stream) {
    const float* x   = (const float*)d_in[0];
    const float* C1  = (const float*)d_in[1];
    const float* W1  = (const float*)d_in[2];
    const float* b1  = (const float*)d_in[3];
    const float* Cs  = (const float*)d_in[4];
    const float* C2  = (const float*)d_in[5];
    const float* W2  = (const float*)d_in[6];
    const float* b2  = (const float*)d_in[7];
    const float* Wr1 = (const float*)d_in[8];
    const float* br1 = (const float*)d_in[9];
    const float* Wr2 = (const float*)d_in[10];
    const float* br2 = (const float*)d_in[11];
    const float* Wr3 = (const float*)d_in[12];
    const float* br3 = (const float*)d_in[13];

    float* out = (float*)d_out;
    float* out0     = out;              // (512,3072) f32 sigmoid output
    float* xsum_out = out + OUT0_SZ;    // (512,2560) f32 x_sum

    // workspace layout (bytes)
    char* base = (char*)d_ws;
    unsigned short* xrec = (unsigned short*)(base);               // 512*2576*2  = 2,637,824
    unsigned short* h1   = (unsigned short*)(base +   2637824);   // 512*5136*2  = 5,259,264
    unsigned short* h2   = (unsigned short*)(base +   7897088);   // 512*4112*2  = 4,210,688
    unsigned short* Wt1  = (unsigned short*)(base +  12107776);   // 5120*2576*2 = 26,378,240
    unsigned short* Wt2  = (unsigned short*)(base +  38486016);   // 4096*5136*2 = 42,074,112
    unsigned short* Wt3  = (unsigned short*)(base +  80560128);   // 3072*4112*2 = 25,264,128
    float*          Pbuf = (float*)(base + 105824256);            // 4*512*4224*4= 34,603,008
    unsigned short* xp   = (unsigned short*)(base + 140427264);   // 512*3072*2  = 3,145,728
    unsigned short* W1t  = (unsigned short*)(base + 143572992);   //     393,216
    unsigned short* W2t  = (unsigned short*)(base + 143966208);   //     327,680
    float*          part8= (float*)(base + 144293888);            //     163,840
    int*  active = (int*)(base + 144457728);                      //       2,048
    int*  perm   = active + 512;                                  //       2,048
    int4* slots  = (int4*)(perm + 512);                           //         288
    // total ~144.5 MB

    #define CARGS Wr1, Wt1, Wr2, Wt2, Wr3, Wt3

    // capsule weight transposes (needed by caps path)
    conv_small<<<88, 256, 0, stream>>>(W1, W1t, W2, W2t);

    // capsule path + co-scheduled MLP-weight transpose guests.
    // T1 (Wt1, 3200 tiles): caps1 1600 + caps2 1600  -> done before gemm_l1
    // T2 (Wt2, 5120): mask 1300 + bucket 1300 + gemm_l1 2520 -> before L2 gemm
    // T3 (Wt3, 3072): L2 gemm 2000 + combine-L2 1072 -> before L3 gemm
    caps_gemm1_f<<<192 + 1600, 256, 0, stream>>>(x, C1, W1t, b1, xp, 192, 0, CARGS);
    caps_gemm2_f<<<160 + 1600, 256, 0, stream>>>(xp, Cs, C2, W2t, b2, xsum_out, part8, 160, 1600, CARGS);
    mask_f<<<512 + 1300, 256, 0, stream>>>(xsum_out, part8, xrec, active, 512, 3200, CARGS);
    bucket_f<<<1 + 1300, 256, 0, stream>>>(active, perm, slots, 1, 4500, CARGS);

    // MLP layer 1 (grouped, K=256) -> h1 (permuted rows)
    gemm_l1_f<<<720 + 2520, 256, 0, stream>>>(xrec, perm, slots, Wt1, br1, h1, 720, 5800, CARGS);

    // MLP layer 2: (512,5120) @ Wt2^T -> h2
    gemm_splitk_f<<<1024 + 2000, 256, 0, stream>>>(h1, LD_H1, Wt2, KP2, Pbuf, LDP2, 4096, 5120 / SPLITK, 32, 1024, 8320, CARGS);
    combine_f<0><<<2048 + 1072, 256, 0, stream>>>(Pbuf, LDP2, br2, h2, LD_H2, 4096, 4000, nullptr, 2048, 10320, CARGS);

    // MLP layer 3: (512,4096) @ Wt3^T -> out0 (un-permuted)
    gemm_splitk_f<<<768, 256, 0, stream>>>(h2, LD_H2, Wt3, KP3, Pbuf, LDP3, 3072, 4096 / SPLITK, 24, 768, 0, CARGS);
    combine_f<1><<<1536, 256, 0, stream>>>(Pbuf, LDP3, br3, out0, 3072, 3072, 3072, perm, 1536, 0, CARGS);
}

// Round 5
// 385.685 us; speedup vs baseline: 1.0729x; 1.0729x over previous
//
#include <hip/hip_runtime.h>
#include <math.h>

// B=512, IN_CORES=12, N_PRIM=12, N_PAR=10, RFPC=4, RF=64, CAP=256
// out = concat( sigmoid MLP output (512,3072) f32 , x_sum (512,2560) f32 )
//
// R5 changes vs R4 (414 us) / R3 (392 us):
//  1. MLP weight transpose ELIMINATED (was 270MB traffic + ~89us stall-bound
//     CU time as standalone/guests). GEMMs stage B directly from f32 [K][N]
//     weights: coalesced float4 row loads -> regs -> bf16 convert + k-quad
//     pack -> swizzled ds_write_b64 into [n][k] LDS tiles. Weights read once.
//  2. B LDS layout: [128][40] bf16, k-quad uint2 at idx n*10 + (kq ^
//     ((f4c&3)<<1)) -> ds_read_b128 fragments stay contiguous (XOR only on
//     kq bits 1-2), write conflicts ~4-way.
//  3. K-loop: T14 split. Issue A GLD16 + B float4 loads for tile k+1, MFMA
//     tile k, then convert+write B(k+1), one barrier per step.
//  4. Guest-fusion machinery removed (no more transpose work to hide).

#define BATCH 512
#define OUT0_SZ (512*3072)

#define LD_XREC 2576
#define LD_H1 5136
#define LD_H2 4112
#define LDP2 4224    // Pbuf f32 stride for L2 (16896 B)
#define LDP3 3200    // Pbuf f32 stride for L3 (12800 B)
#define SPLITK 4

typedef __attribute__((ext_vector_type(8))) short short8;   // 8 x bf16
typedef __attribute__((ext_vector_type(4))) float f32x4;

__device__ inline unsigned short f2bf(float f) {
    union { float f; unsigned u; } v; v.f = f;
    unsigned r = v.u + 0x7fffu + ((v.u >> 16) & 1u);   // RNE
    return (unsigned short)(r >> 16);
}
__device__ inline float bf2f(unsigned int hi16) {
    union { unsigned u; float f; } v; v.u = hi16 << 16; return v.f;
}

#define GLD16(g, l) __builtin_amdgcn_global_load_lds( \
    (const __attribute__((address_space(1))) unsigned int*)(g), \
    (__attribute__((address_space(3))) unsigned int*)(l), 16, 0, 0)

// ---------------------------------------------------------------------------
// B staging: f32 [K][N] global -> bf16 [n][k] LDS (stride 40), converted.
// Thread: kq = tid>>5 (k-quad 0..7), f4c = tid&31 (float4 col chunk).
// Loads 4 rows x float4 (coalesced 512B/row per wave). Pack k-quads into
// uint2; write at uint2 idx n*10 + (kq ^ ((f4c&3)<<1))  [XOR preserves
// b128-read contiguity; spreads write banks to ~4-way].
// ---------------------------------------------------------------------------
struct BReg { float4 r0, r1, r2, r3; };

__device__ inline void loadB(BReg& br, const float* B, int ldB, int Kr, int Nr,
                             int k0, int bn, int tid)
{
    int kq = tid >> 5, f4c = tid & 31;
    int ka = k0 + kq * 4;
    int nb = bn + f4c * 4;
    float4 z = make_float4(0.f, 0.f, 0.f, 0.f);
    br.r0 = z; br.r1 = z; br.r2 = z; br.r3 = z;
    const float* p = B + (size_t)ka * ldB + nb;
    if (nb + 3 < Nr) {
        if (ka + 3 < Kr) {
            br.r0 = *(const float4*)p;
            br.r1 = *(const float4*)(p + ldB);
            br.r2 = *(const float4*)(p + 2 * (size_t)ldB);
            br.r3 = *(const float4*)(p + 3 * (size_t)ldB);
        } else {
            if (ka     < Kr) br.r0 = *(const float4*)p;
            if (ka + 1 < Kr) br.r1 = *(const float4*)(p + ldB);
            if (ka + 2 < Kr) br.r2 = *(const float4*)(p + 2 * (size_t)ldB);
            if (ka + 3 < Kr) br.r3 = *(const float4*)(p + 3 * (size_t)ldB);
        }
    } else {
        float t[4][4] = {};
        #pragma unroll
        for (int e = 0; e < 4; ++e)
            if (ka + e < Kr)
                #pragma unroll
                for (int j = 0; j < 4; ++j)
                    if (nb + j < Nr) t[e][j] = B[(size_t)(ka + e) * ldB + nb + j];
        br.r0 = make_float4(t[0][0], t[0][1], t[0][2], t[0][3]);
        br.r1 = make_float4(t[1][0], t[1][1], t[1][2], t[1][3]);
        br.r2 = make_float4(t[2][0], t[2][1], t[2][2], t[2][3]);
        br.r3 = make_float4(t[3][0], t[3][1], t[3][2], t[3][3]);
    }
}

__device__ inline void writeB(const BReg& br, unsigned short* Bs, int tid)
{
    int kq = tid >> 5, f4c = tid & 31;
    int kqs = kq ^ ((f4c & 3) << 1);
    uint2* B2 = (uint2*)Bs;
    float a0[4] = {br.r0.x, br.r0.y, br.r0.z, br.r0.w};
    float a1[4] = {br.r1.x, br.r1.y, br.r1.z, br.r1.w};
    float a2[4] = {br.r2.x, br.r2.y, br.r2.z, br.r2.w};
    float a3[4] = {br.r3.x, br.r3.y, br.r3.z, br.r3.w};
    #pragma unroll
    for (int j = 0; j < 4; ++j) {
        unsigned int u0 = (unsigned)f2bf(a0[j]) | ((unsigned)f2bf(a1[j]) << 16);
        unsigned int u1 = (unsigned)f2bf(a2[j]) | ((unsigned)f2bf(a3[j]) << 16);
        B2[(f4c * 4 + j) * 10 + kqs] = make_uint2(u0, u1);
    }
}

__device__ inline short8 readB(const unsigned short* Bs, int n, int q)
{
    int sw = ((n >> 2) & 3) << 1;
    return *(const short8*)&Bs[n * 40 + ((2 * q) ^ sw) * 4];
}

// ---------------------------------------------------------------------------
// Capsule weight transposes W1 (48) + W2 (40), 64x64 each, LDS-free.
// ---------------------------------------------------------------------------
__global__ __launch_bounds__(256) void conv_small(
    const float* __restrict__ W1, unsigned short* __restrict__ W1t,
    const float* __restrict__ W2, unsigned short* __restrict__ W2t)
{
    int bid = blockIdx.x;
    const float* W; unsigned short* Wt;
    if (bid < 48) { W = W1 + (size_t)bid * 4096; Wt = W1t + (size_t)bid * 4096; }
    else          { W = W2 + (size_t)(bid - 48) * 4096; Wt = W2t + (size_t)(bid - 48) * 4096; }
    int tid = threadIdx.x;
    int nr = tid >> 2;
    int kc = (tid & 3) * 16;
    float v[16];
    #pragma unroll
    for (int i = 0; i < 16; ++i)
        v[i] = W[(size_t)(kc + i) * 64 + nr];
    unsigned int u[8];
    #pragma unroll
    for (int j = 0; j < 8; ++j)
        u[j] = (unsigned int)f2bf(v[2 * j]) | ((unsigned int)f2bf(v[2 * j + 1]) << 16);
    unsigned int* dst = (unsigned int*)&Wt[(size_t)nr * 64 + kc];
    *(uint4*)(dst)     = make_uint4(u[0], u[1], u[2], u[3]);
    *(uint4*)(dst + 4) = make_uint4(u[4], u[5], u[6], u[7]);
}

// ---------------------------------------------------------------------------
// Capsule layer 1. Grid (48 kl, 4 m-tiles), 256 thr.
// ---------------------------------------------------------------------------
__global__ __launch_bounds__(256) void caps_gemm1(
    const float* __restrict__ x, const float* __restrict__ C1,
    const unsigned short* __restrict__ W1t, const float* __restrict__ b1,
    unsigned short* __restrict__ xp)
{
    __shared__ __align__(16) unsigned short As[128 * 72];
    __shared__ __align__(16) unsigned short Bs[64 * 72];
    __shared__ float Csh[48];
    int kl = blockIdx.x;
    int bm = blockIdx.y * 128;
    int tid = threadIdx.x;
    int w = tid >> 6, lane = tid & 63, q = lane >> 4, r16 = lane & 15;
    int wm = (w >> 1) * 64, wn = (w & 1) * 32;

    if (tid < 48) Csh[tid] = C1[tid * 48 + kl];
    {
        const uint4* src = (const uint4*)(W1t + (size_t)kl * 4096);
        #pragma unroll
        for (int p = 0; p < 2; ++p) {
            int c = tid + p * 256;
            int row = c >> 3, cq = c & 7;
            *(uint4*)&Bs[row * 72 + cq * 8] = src[c];
        }
    }
    __syncthreads();

    int arow = tid >> 1, ah = (tid & 1) * 32;
    float accp[32];
    #pragma unroll
    for (int i = 0; i < 32; ++i) accp[i] = 0.f;
    const float* xrow = x + (size_t)(bm + arow) * 3072 + ah;
    for (int ij = 0; ij < 48; ++ij) {
        float c = Csh[ij];
        if (c != 0.f) {
            const float4* p4 = (const float4*)(xrow + ij * 64);
            #pragma unroll
            for (int cc = 0; cc < 8; ++cc) {
                float4 v = p4[cc];
                accp[cc * 4 + 0] = fmaf(c, v.x, accp[cc * 4 + 0]);
                accp[cc * 4 + 1] = fmaf(c, v.y, accp[cc * 4 + 1]);
                accp[cc * 4 + 2] = fmaf(c, v.z, accp[cc * 4 + 2]);
                accp[cc * 4 + 3] = fmaf(c, v.w, accp[cc * 4 + 3]);
            }
        }
    }
    {
        unsigned short* dst = &As[arow * 72 + ah];
        #pragma unroll
        for (int cc = 0; cc < 4; ++cc) {
            unsigned int u[4];
            #pragma unroll
            for (int j = 0; j < 4; ++j)
                u[j] = (unsigned int)f2bf(accp[cc * 8 + 2 * j]) |
                       ((unsigned int)f2bf(accp[cc * 8 + 2 * j + 1]) << 16);
            *(uint4*)&dst[cc * 8] = make_uint4(u[0], u[1], u[2], u[3]);
        }
    }
    __syncthreads();

    f32x4 acc[4][2];
    #pragma unroll
    for (int i = 0; i < 4; ++i)
        #pragma unroll
        for (int j = 0; j < 2; ++j) acc[i][j] = (f32x4)0.f;
    #pragma unroll
    for (int ks = 0; ks < 2; ++ks) {
        short8 a[4], b[2];
        #pragma unroll
        for (int mt = 0; mt < 4; ++mt)
            a[mt] = *(const short8*)&As[(wm + mt * 16 + r16) * 72 + ks * 32 + q * 8];
        #pragma unroll
        for (int nt = 0; nt < 2; ++nt)
            b[nt] = *(const short8*)&Bs[(wn + nt * 16 + r16) * 72 + ks * 32 + q * 8];
        #pragma unroll
        for (int mt = 0; mt < 4; ++mt)
            #pragma unroll
            for (int nt = 0; nt < 2; ++nt)
                acc[mt][nt] = __builtin_amdgcn_mfma_f32_16x16x32_bf16(a[mt], b[nt], acc[mt][nt], 0, 0, 0);
    }

    #pragma unroll
    for (int mt = 0; mt < 4; ++mt) {
        #pragma unroll
        for (int nt = 0; nt < 2; ++nt) {
            int n = wn + nt * 16 + r16;
            float bv = b1[kl * 64 + n];
            #pragma unroll
            for (int reg = 0; reg < 4; ++reg) {
                int row = bm + wm + mt * 16 + q * 4 + reg;
                xp[(size_t)row * 3072 + kl * 64 + n] = f2bf(fmaxf(acc[mt][nt][reg] + bv, 0.f));
            }
        }
    }
}

// ---------------------------------------------------------------------------
// Capsule layer 2 + skip + norms. Grid (40 kl, 4 m-tiles), 256 thr.
// Skip written directly to xsum, read back after barrier.
// ---------------------------------------------------------------------------
__global__ __launch_bounds__(256) void caps_gemm2(
    const unsigned short* __restrict__ xp, const float* __restrict__ Cs,
    const float* __restrict__ C2, const unsigned short* __restrict__ W2t,
    const float* __restrict__ b2, float* __restrict__ xsum,
    float* __restrict__ part8)
{
    __shared__ __align__(16) unsigned short As[128 * 72];
    __shared__ __align__(16) unsigned short Bs[64 * 72];
    __shared__ float C2sh[48], Cssh[48];
    int kl = blockIdx.x;
    int bm = blockIdx.y * 128;
    int tid = threadIdx.x;
    int w = tid >> 6, lane = tid & 63, q = lane >> 4, r16 = lane & 15;
    int wm = (w >> 1) * 64, wn = (w & 1) * 32;
    int half = w & 1;

    if (tid < 48) { C2sh[tid] = C2[tid * 40 + kl]; Cssh[tid] = Cs[tid * 40 + kl]; }
    {
        const uint4* src = (const uint4*)(W2t + (size_t)kl * 4096);
        #pragma unroll
        for (int p = 0; p < 2; ++p) {
            int c = tid + p * 256;
            int row = c >> 3, cq = c & 7;
            *(uint4*)&Bs[row * 72 + cq * 8] = src[c];
        }
    }
    __syncthreads();

    int arow = tid >> 1, ah = (tid & 1) * 32;
    float accp[32], skp[32];
    #pragma unroll
    for (int i = 0; i < 32; ++i) { accp[i] = 0.f; skp[i] = 0.f; }
    const unsigned short* xprow = xp + (size_t)(bm + arow) * 3072 + ah;
    for (int ij = 0; ij < 48; ++ij) {
        float c2 = C2sh[ij], cs = Cssh[ij];
        if (c2 != 0.f || cs != 0.f) {
            const uint4* p4 = (const uint4*)(xprow + ij * 64);
            #pragma unroll
            for (int cc = 0; cc < 4; ++cc) {
                uint4 v = p4[cc];
                unsigned int uu[4] = {v.x, v.y, v.z, v.w};
                #pragma unroll
                for (int j = 0; j < 4; ++j) {
                    float lo = bf2f(uu[j] & 0xffffu);
                    float hi = bf2f(uu[j] >> 16);
                    int idx = cc * 8 + 2 * j;
                    accp[idx]     = fmaf(c2, lo, accp[idx]);
                    accp[idx + 1] = fmaf(c2, hi, accp[idx + 1]);
                    skp[idx]      = fmaf(cs, lo, skp[idx]);
                    skp[idx + 1]  = fmaf(cs, hi, skp[idx + 1]);
                }
            }
        }
    }
    {
        unsigned short* dst = &As[arow * 72 + ah];
        #pragma unroll
        for (int cc = 0; cc < 4; ++cc) {
            unsigned int u[4];
            #pragma unroll
            for (int j = 0; j < 4; ++j)
                u[j] = (unsigned int)f2bf(accp[cc * 8 + 2 * j]) |
                       ((unsigned int)f2bf(accp[cc * 8 + 2 * j + 1]) << 16);
            *(uint4*)&dst[cc * 8] = make_uint4(u[0], u[1], u[2], u[3]);
        }
        float* sx = xsum + (size_t)(bm + arow) * 2560 + kl * 64 + ah;
        #pragma unroll
        for (int cc = 0; cc < 8; ++cc)
            *(float4*)&sx[cc * 4] = make_float4(skp[cc*4], skp[cc*4+1], skp[cc*4+2], skp[cc*4+3]);
    }
    __syncthreads();

    f32x4 acc[4][2];
    #pragma unroll
    for (int i = 0; i < 4; ++i)
        #pragma unroll
        for (int j = 0; j < 2; ++j) acc[i][j] = (f32x4)0.f;
    #pragma unroll
    for (int ks = 0; ks < 2; ++ks) {
        short8 a[4], b[2];
        #pragma unroll
        for (int mt = 0; mt < 4; ++mt)
            a[mt] = *(const short8*)&As[(wm + mt * 16 + r16) * 72 + ks * 32 + q * 8];
        #pragma unroll
        for (int nt = 0; nt < 2; ++nt)
            b[nt] = *(const short8*)&Bs[(wn + nt * 16 + r16) * 72 + ks * 32 + q * 8];
        #pragma unroll
        for (int mt = 0; mt < 4; ++mt)
            #pragma unroll
            for (int nt = 0; nt < 2; ++nt)
                acc[mt][nt] = __builtin_amdgcn_mfma_f32_16x16x32_bf16(a[mt], b[nt], acc[mt][nt], 0, 0, 0);
    }

    #pragma unroll
    for (int mt = 0; mt < 4; ++mt) {
        float sreg[4] = {0.f, 0.f, 0.f, 0.f};
        #pragma unroll
        for (int nt = 0; nt < 2; ++nt) {
            int n = wn + nt * 16 + r16;
            float bv = b2[kl * 64 + n];
            #pragma unroll
            for (int reg = 0; reg < 4; ++reg) {
                int lr = wm + mt * 16 + q * 4 + reg;
                size_t xi = (size_t)(bm + lr) * 2560 + kl * 64 + n;
                float v = xsum[xi] + fmaxf(acc[mt][nt][reg] + bv, 0.f);
                xsum[xi] = v;
                sreg[reg] += v * v;
            }
        }
        #pragma unroll
        for (int reg = 0; reg < 4; ++reg) {
            float s = sreg[reg];
            s += __shfl_xor(s, 1); s += __shfl_xor(s, 2);
            s += __shfl_xor(s, 4); s += __shfl_xor(s, 8);
            if (r16 == 0) {
                int row = bm + wm + mt * 16 + q * 4 + reg;
                part8[(size_t)row * 80 + kl * 2 + half] = s;
            }
        }
    }
}

// ---------------------------------------------------------------------------
// Norm-argmax; writes only the active 256-capsule slice of xrec (bf16).
// ---------------------------------------------------------------------------
__global__ __launch_bounds__(256) void mask_kernel(
    const float* __restrict__ xs, const float* __restrict__ part8,
    unsigned short* __restrict__ xrec, int* __restrict__ active)
{
    int b = blockIdx.x;
    int tid = threadIdx.x;
    __shared__ float norms[10];
    __shared__ int act_sh;
    if (tid < 10) {
        float s = 0.f;
        #pragma unroll
        for (int j = 0; j < 8; ++j) s += part8[(size_t)b * 80 + tid * 8 + j];
        norms[tid] = s;
    }
    __syncthreads();
    if (tid == 0) {
        int best = 0; float bn = -1.f;
        #pragma unroll
        for (int k = 0; k < 10; ++k)
            if (norms[k] > bn) { bn = norms[k]; best = k; }
        act_sh = best;
        active[b] = best;
    }
    __syncthreads();
    int act = act_sh;
    int idx = act * 256 + tid;
    xrec[(size_t)b * LD_XREC + idx] = f2bf(xs[(size_t)b * 2560 + idx]);
}

// ---------------------------------------------------------------------------
// Bucket rows by active capsule: perm + slot table (<=18 slots).
// ---------------------------------------------------------------------------
__global__ __launch_bounds__(512) void bucket_kernel(
    const int* __restrict__ active, int* __restrict__ perm,
    int4* __restrict__ slots)
{
    __shared__ int cnt[10], pos[10];
    int tid = threadIdx.x;
    if (tid < 10) cnt[tid] = 0;
    __syncthreads();
    int a = active[tid];
    atomicAdd(&cnt[a], 1);
    __syncthreads();
    if (tid == 0) {
        int o = 0, s = 0;
        for (int g = 0; g < 10; ++g) {
            pos[g] = o;
            int mg = cnt[g];
            for (int t0 = 0; t0 < mg; t0 += 64)
                slots[s++] = make_int4(g, o + t0, min(64, mg - t0), 0);
            o += mg;
        }
        for (; s < 18; ++s) slots[s] = make_int4(0, 0, 0, 0);
    }
    __syncthreads();
    int r = atomicAdd(&pos[a], 1);
    perm[r] = tid;
}

// ---------------------------------------------------------------------------
// Grouped MLP layer-1 GEMM: per slot (<=64 permuted rows, capsule g),
// K=256 from xrec bf16 (A, GLD16) x Wr1 f32 rows g*256..+256 (B, converted
// in staging). Tile 64x128, 4 waves 32x64. Fused bias+relu -> h1 bf16.
// ---------------------------------------------------------------------------
__global__ __launch_bounds__(256) void gemm_l1(
    const unsigned short* __restrict__ xrec, const int* __restrict__ perm,
    const int4* __restrict__ slots, const float* __restrict__ Wr1,
    const float* __restrict__ br1, unsigned short* __restrict__ h1)
{
    __shared__ __align__(16) unsigned short As[2][64 * 32];
    __shared__ __align__(16) unsigned short Bs[2][128 * 40];
    __shared__ int rows[64];

    int4 s = slots[blockIdx.y];
    if (s.z == 0) return;
    int g = s.x, mstart = s.y, mval = s.z;
    int bn = blockIdx.x * 128;
    int tid = threadIdx.x;

    if (tid < 64) rows[tid] = perm[mstart + min(tid, mval - 1)];
    __syncthreads();

    int w = tid >> 6, lane = tid & 63;
    int wm = (w >> 1) * 32, wn = (w & 1) * 64;
    int q = lane >> 4, r16 = lane & 15;
    int srow = tid >> 2, skq = tid & 3;

    f32x4 acc[2][4];
    #pragma unroll
    for (int i = 0; i < 2; ++i)
        #pragma unroll
        for (int j = 0; j < 4; ++j) acc[i][j] = (f32x4)0.f;

    int arow = rows[srow];
    const unsigned short* ga = xrec + (size_t)arow * LD_XREC + g * 256 + skq * 8;
    int kbase = g * 256;

    BReg br;
    loadB(br, Wr1, 5000, 2560, 5000, kbase, bn, tid);
    GLD16(ga, &As[0][tid * 8]);
    writeB(br, Bs[0], tid);
    __syncthreads();

    int cur = 0;
    for (int kk = 32; kk <= 256; kk += 32) {
        bool more = kk < 256;
        if (more) {
            GLD16(ga + kk, &As[cur ^ 1][tid * 8]);
            loadB(br, Wr1, 5000, 2560, 5000, kbase + kk, bn, tid);
        }
        short8 a[2], b[4];
        #pragma unroll
        for (int mt = 0; mt < 2; ++mt)
            a[mt] = *(const short8*)&As[cur][(wm + mt * 16 + r16) * 32 + q * 8];
        #pragma unroll
        for (int nt = 0; nt < 4; ++nt)
            b[nt] = readB(Bs[cur], wn + nt * 16 + r16, q);
        #pragma unroll
        for (int mt = 0; mt < 2; ++mt)
            #pragma unroll
            for (int nt = 0; nt < 4; ++nt)
                acc[mt][nt] = __builtin_amdgcn_mfma_f32_16x16x32_bf16(a[mt], b[nt], acc[mt][nt], 0, 0, 0);
        if (more) writeB(br, Bs[cur ^ 1], tid);
        __syncthreads();
        cur ^= 1;
    }

    #pragma unroll
    for (int mt = 0; mt < 2; ++mt) {
        #pragma unroll
        for (int nt = 0; nt < 4; ++nt) {
            int n = bn + wn + nt * 16 + r16;
            float bv = (n < 5000) ? br1[n] : 0.f;
            #pragma unroll
            for (int reg = 0; reg < 4; ++reg) {
                int lm = wm + mt * 16 + q * 4 + reg;
                if (lm < mval)
                    h1[(size_t)(mstart + lm) * LD_H1 + n] =
                        f2bf(fmaxf(acc[mt][nt][reg] + bv, 0.f));
            }
        }
    }
}

// ---------------------------------------------------------------------------
// Split-K MFMA GEMM, 64(M)x128(N) tile, BK=32. A bf16 (GLD16), B f32 [K][N]
// converted in staging. Grid (Np/128, 8, SPLITK).
// ---------------------------------------------------------------------------
__global__ __launch_bounds__(256) void gemm_splitk(
    const unsigned short* __restrict__ A, int ldA,
    const float* __restrict__ B, int ldB, int Kr, int Nr,
    float* __restrict__ P, int ldP, int kper)
{
    __shared__ __align__(16) unsigned short As[2][64 * 32];
    __shared__ __align__(16) unsigned short Bs[2][128 * 40];

    int tid = threadIdx.x;
    int bn = blockIdx.x * 128;
    int bm = blockIdx.y * 64;
    int kz = blockIdx.z * kper;

    int w = tid >> 6, lane = tid & 63;
    int wm = (w >> 1) * 32, wn = (w & 1) * 64;
    int q = lane >> 4, r16 = lane & 15;
    int srow = tid >> 2, skq = tid & 3;

    f32x4 acc[2][4];
    #pragma unroll
    for (int i = 0; i < 2; ++i)
        #pragma unroll
        for (int j = 0; j < 4; ++j) acc[i][j] = (f32x4)0.f;

    const unsigned short* ga = A + (size_t)(bm + srow) * ldA + kz + skq * 8;

    BReg br;
    loadB(br, B, ldB, Kr, Nr, kz, bn, tid);
    GLD16(ga, &As[0][tid * 8]);
    writeB(br, Bs[0], tid);
    __syncthreads();

    int cur = 0;
    for (int kk = 32; kk <= kper; kk += 32) {
        bool more = kk < kper;
        if (more) {
            GLD16(ga + kk, &As[cur ^ 1][tid * 8]);
            loadB(br, B, ldB, Kr, Nr, kz + kk, bn, tid);
        }
        short8 a[2], b[4];
        #pragma unroll
        for (int mt = 0; mt < 2; ++mt)
            a[mt] = *(const short8*)&As[cur][(wm + mt * 16 + r16) * 32 + q * 8];
        #pragma unroll
        for (int nt = 0; nt < 4; ++nt)
            b[nt] = readB(Bs[cur], wn + nt * 16 + r16, q);
        #pragma unroll
        for (int mt = 0; mt < 2; ++mt)
            #pragma unroll
            for (int nt = 0; nt < 4; ++nt)
                acc[mt][nt] = __builtin_amdgcn_mfma_f32_16x16x32_bf16(a[mt], b[nt], acc[mt][nt], 0, 0, 0);
        if (more) writeB(br, Bs[cur ^ 1], tid);
        __syncthreads();
        cur ^= 1;
    }

    float* Pz = P + (size_t)blockIdx.z * 512 * ldP;
    #pragma unroll
    for (int mt = 0; mt < 2; ++mt) {
        #pragma unroll
        for (int nt = 0; nt < 4; ++nt) {
            int cn = bn + wn + nt * 16 + r16;
            #pragma unroll
            for (int reg = 0; reg < 4; ++reg) {
                int cm = bm + wm + mt * 16 + q * 4 + reg;
                Pz[(size_t)cm * ldP + cn] = acc[mt][nt][reg];
            }
        }
    }
}

// ---------------------------------------------------------------------------
// Combine split-K partials + bias + act.
// MODE 0: relu->bf16 (stride ldO). MODE 1: sigmoid->f32, un-permute rows.
// ---------------------------------------------------------------------------
template<int MODE>
__global__ __launch_bounds__(256) void combine_kernel(
    const float* __restrict__ P, int ldP, const float* __restrict__ bias,
    void* __restrict__ out, int ldO, int Np, int N_real,
    const int* __restrict__ perm)
{
    int gid = blockIdx.x * 256 + threadIdx.x;
    int n0 = (gid * 4) % Np;
    int m  = (gid * 4) / Np;
    size_t MN = (size_t)512 * ldP;
    const float* p = P + (size_t)m * ldP + n0;
    f32x4 s = *(const f32x4*)p;
    s += *(const f32x4*)(p + MN);
    s += *(const f32x4*)(p + 2 * MN);
    s += *(const f32x4*)(p + 3 * MN);
    f32x4 bv = (n0 < N_real) ? *(const f32x4*)(bias + n0) : (f32x4)0.f;
    s += bv;
    if (MODE == 0) {
        unsigned int lo = (unsigned int)f2bf(fmaxf(s[0], 0.f)) | ((unsigned int)f2bf(fmaxf(s[1], 0.f)) << 16);
        unsigned int hi = (unsigned int)f2bf(fmaxf(s[2], 0.f)) | ((unsigned int)f2bf(fmaxf(s[3], 0.f)) << 16);
        *(uint2*)((unsigned short*)out + (size_t)m * ldO + n0) = make_uint2(lo, hi);
    } else {
        int row = perm[m];
        f32x4 v;
        v[0] = 1.f / (1.f + expf(-s[0]));
        v[1] = 1.f / (1.f + expf(-s[1]));
        v[2] = 1.f / (1.f + expf(-s[2]));
        v[3] = 1.f / (1.f + expf(-s[3]));
        *(f32x4*)((float*)out + (size_t)row * ldO + n0) = v;
    }
}

extern "C" void kernel_launch(void* const* d_in, const int* in_sizes, int n_in,
                              void* d_out, int out_size, void* d_ws, size_t ws_size,
                              hipStream_t stream) {
    const float* x   = (const float*)d_in[0];
    const float* C1  = (const float*)d_in[1];
    const float* W1  = (const float*)d_in[2];
    const float* b1  = (const float*)d_in[3];
    const float* Cs  = (const float*)d_in[4];
    const float* C2  = (const float*)d_in[5];
    const float* W2  = (const float*)d_in[6];
    const float* b2  = (const float*)d_in[7];
    const float* Wr1 = (const float*)d_in[8];
    const float* br1 = (const float*)d_in[9];
    const float* Wr2 = (const float*)d_in[10];
    const float* br2 = (const float*)d_in[11];
    const float* Wr3 = (const float*)d_in[12];
    const float* br3 = (const float*)d_in[13];

    float* out = (float*)d_out;
    float* out0     = out;              // (512,3072) f32 sigmoid output
    float* xsum_out = out + OUT0_SZ;    // (512,2560) f32 x_sum

    // workspace layout (bytes)
    char* base = (char*)d_ws;
    unsigned short* xrec = (unsigned short*)(base);               // 512*2576*2 = 2,637,824
    unsigned short* h1   = (unsigned short*)(base +  2637824);    // 512*5136*2 = 5,259,264
    unsigned short* h2   = (unsigned short*)(base +  7897088);    // 512*4112*2 = 4,210,688
    unsigned short* xp   = (unsigned short*)(base + 12107776);    // 512*3072*2 = 3,145,728
    unsigned short* W1t  = (unsigned short*)(base + 15253504);    //    393,216
    unsigned short* W2t  = (unsigned short*)(base + 15646720);    //    327,680
    float*          part8= (float*)(base + 15974400);             //    163,840
    int*  active = (int*)(base + 16138240);                       //      2,048
    int*  perm   = active + 512;                                  //      2,048
    int4* slots  = (int4*)(perm + 512);                           //        288
    float*          Pbuf = (float*)(base + 16144384);             // 4*512*4224*4 = 34,603,008
    // total ~50.7 MB

    // capsule weight transposes (tiny)
    conv_small<<<88, 256, 0, stream>>>(W1, W1t, W2, W2t);

    // capsule path
    caps_gemm1<<<dim3(48, 4), 256, 0, stream>>>(x, C1, W1t, b1, xp);
    caps_gemm2<<<dim3(40, 4), 256, 0, stream>>>(xp, Cs, C2, W2t, b2, xsum_out, part8);
    mask_kernel<<<BATCH, 256, 0, stream>>>(xsum_out, part8, xrec, active);
    bucket_kernel<<<1, 512, 0, stream>>>(active, perm, slots);

    // MLP layer 1 (grouped, K=256, B from Wr1 f32) -> h1 (permuted rows)
    gemm_l1<<<dim3(5120 / 128, 18), 256, 0, stream>>>(xrec, perm, slots, Wr1, br1, h1);

    // MLP layer 2: (512,5120 bf16) x Wr2 f32 [5000][4000] -> h2
    gemm_splitk<<<dim3(4096 / 128, 8, SPLITK), 256, 0, stream>>>(
        h1, LD_H1, Wr2, 4000, 5000, 4000, Pbuf, LDP2, 5120 / SPLITK);
    combine_kernel<0><<<512 * 4096 / 1024, 256, 0, stream>>>(
        Pbuf, LDP2, br2, h2, LD_H2, 4096, 4000, nullptr);

    // MLP layer 3: (512,4096 bf16) x Wr3 f32 [4000][3072] -> out0 (un-permuted)
    gemm_splitk<<<dim3(3072 / 128, 8, SPLITK), 256, 0, stream>>>(
        h2, LD_H2, Wr3, 3072, 4000, 3072, Pbuf, LDP3, 4096 / SPLITK);
    combine_kernel<1><<<512 * 3072 / 1024, 256, 0, stream>>>(
        Pbuf, LDP3, br3, out0, 3072, 3072, 3072, perm);
}

// Round 6
// 344.650 us; speedup vs baseline: 1.2006x; 1.1191x over previous
//
#include <hip/hip_runtime.h>
#include <math.h>

// B=512, IN_CORES=12, N_PRIM=12, N_PAR=10, RFPC=4, RF=64, CAP=256
// out = concat( sigmoid MLP output (512,3072) f32 , x_sum (512,2560) f32 )
//
// R6 changes vs R5 (386 us):
//  1. gemm_splitk -> gemm_big: BM=256 x BN=128 tile (was 64x128). B re-read
//     factor 8x -> 2x, cache-aggregate traffic 800 -> 320 MB (R5 was
//     cache-BW-bound at ~8.5 TB/s aggregate, NOT latency-bound).
//  2. XCD-pair decode: the 2 m-blocks sharing a (bn,z) B-slice get bids
//     congruent mod 8 -> same XCD -> 2nd read is L2-local.
//  3. Bank-conflict-free swizzles: B sw(n)=((n>>3)&3)<<1 (write was 8-way,
//     11.8M conflict cycles); A staged with pre-swizzled GLD16 source
//     (granule k8 ^ ((row>>1)&3)) -> conflict-free a-frag reads.
//  4. z=8 split-K (2 blocks/CU), 2-deep B register prefetch, 2-step
//     unrolled (static regs).

#define BATCH 512
#define OUT0_SZ (512*3072)

#define LD_XREC 2576
#define LD_H1 5136
#define LD_H2 4112
#define LDP2 4224    // Pbuf f32 stride for L2
#define LDP3 3200    // Pbuf f32 stride for L3
#define NZ 8         // split-K factor

typedef __attribute__((ext_vector_type(8))) short short8;   // 8 x bf16
typedef __attribute__((ext_vector_type(4))) float f32x4;

__device__ inline unsigned short f2bf(float f) {
    union { float f; unsigned u; } v; v.f = f;
    unsigned r = v.u + 0x7fffu + ((v.u >> 16) & 1u);   // RNE
    return (unsigned short)(r >> 16);
}
__device__ inline float bf2f(unsigned int hi16) {
    union { unsigned u; float f; } v; v.u = hi16 << 16; return v.f;
}

#define GLD16(g, l) __builtin_amdgcn_global_load_lds( \
    (const __attribute__((address_space(1))) unsigned int*)(g), \
    (__attribute__((address_space(3))) unsigned int*)(l), 16, 0, 0)

// ---------------------------------------------------------------------------
// B staging: f32 [K][N] global -> bf16 [n][k] LDS (stride 40 shorts).
// Thread: kq = tid>>5 (k-quad), f4c = tid&31 (4-col chunk). Swizzle
// sw(n) = ((n>>3)&3)<<1 -> per-8-lane-phase conflict-free write AND read.
// ---------------------------------------------------------------------------
struct BReg { float4 r0, r1, r2, r3; };

__device__ inline void loadB(BReg& br, const float* B, int ldB, int Kr, int Nr,
                             int k0, int bn, int tid)
{
    int kq = tid >> 5, f4c = tid & 31;
    int ka = k0 + kq * 4;
    int nb = bn + f4c * 4;
    float4 z = make_float4(0.f, 0.f, 0.f, 0.f);
    br.r0 = z; br.r1 = z; br.r2 = z; br.r3 = z;
    const float* p = B + (size_t)ka * ldB + nb;
    if (nb + 3 < Nr) {
        if (ka + 3 < Kr) {
            br.r0 = *(const float4*)p;
            br.r1 = *(const float4*)(p + ldB);
            br.r2 = *(const float4*)(p + 2 * (size_t)ldB);
            br.r3 = *(const float4*)(p + 3 * (size_t)ldB);
        } else {
            if (ka     < Kr) br.r0 = *(const float4*)p;
            if (ka + 1 < Kr) br.r1 = *(const float4*)(p + ldB);
            if (ka + 2 < Kr) br.r2 = *(const float4*)(p + 2 * (size_t)ldB);
            if (ka + 3 < Kr) br.r3 = *(const float4*)(p + 3 * (size_t)ldB);
        }
    } else {
        float t[4][4] = {};
        #pragma unroll
        for (int e = 0; e < 4; ++e)
            if (ka + e < Kr)
                #pragma unroll
                for (int j = 0; j < 4; ++j)
                    if (nb + j < Nr) t[e][j] = B[(size_t)(ka + e) * ldB + nb + j];
        br.r0 = make_float4(t[0][0], t[0][1], t[0][2], t[0][3]);
        br.r1 = make_float4(t[1][0], t[1][1], t[1][2], t[1][3]);
        br.r2 = make_float4(t[2][0], t[2][1], t[2][2], t[2][3]);
        br.r3 = make_float4(t[3][0], t[3][1], t[3][2], t[3][3]);
    }
}

__device__ inline void writeB(const BReg& br, unsigned short* Bs, int tid)
{
    int kq = tid >> 5, f4c = tid & 31;
    int kqs = kq ^ (((f4c >> 1) & 3) << 1);   // sw(n)=((n>>3)&3)<<1, n=f4c*4+j
    uint2* B2 = (uint2*)Bs;
    float a0[4] = {br.r0.x, br.r0.y, br.r0.z, br.r0.w};
    float a1[4] = {br.r1.x, br.r1.y, br.r1.z, br.r1.w};
    float a2[4] = {br.r2.x, br.r2.y, br.r2.z, br.r2.w};
    float a3[4] = {br.r3.x, br.r3.y, br.r3.z, br.r3.w};
    #pragma unroll
    for (int j = 0; j < 4; ++j) {
        unsigned int u0 = (unsigned)f2bf(a0[j]) | ((unsigned)f2bf(a1[j]) << 16);
        unsigned int u1 = (unsigned)f2bf(a2[j]) | ((unsigned)f2bf(a3[j]) << 16);
        B2[(f4c * 4 + j) * 10 + kqs] = make_uint2(u0, u1);
    }
}

__device__ inline short8 readB(const unsigned short* Bs, int n, int q)
{
    int sw = ((n >> 3) & 3) << 1;
    return *(const short8*)&Bs[n * 40 + (((2 * q) ^ sw)) * 4];
}

// A fragment read with sigma swizzle (granule k8 stored at k8 ^ ((row>>1)&3))
__device__ inline short8 readA(const unsigned short* As, int row, int q)
{
    return *(const short8*)&As[row * 32 + ((q ^ ((row >> 1) & 3)) * 8)];
}

// ---------------------------------------------------------------------------
// Capsule weight transposes W1 (48) + W2 (40), 64x64 each, LDS-free.
// ---------------------------------------------------------------------------
__global__ __launch_bounds__(256) void conv_small(
    const float* __restrict__ W1, unsigned short* __restrict__ W1t,
    const float* __restrict__ W2, unsigned short* __restrict__ W2t)
{
    int bid = blockIdx.x;
    const float* W; unsigned short* Wt;
    if (bid < 48) { W = W1 + (size_t)bid * 4096; Wt = W1t + (size_t)bid * 4096; }
    else          { W = W2 + (size_t)(bid - 48) * 4096; Wt = W2t + (size_t)(bid - 48) * 4096; }
    int tid = threadIdx.x;
    int nr = tid >> 2;
    int kc = (tid & 3) * 16;
    float v[16];
    #pragma unroll
    for (int i = 0; i < 16; ++i)
        v[i] = W[(size_t)(kc + i) * 64 + nr];
    unsigned int u[8];
    #pragma unroll
    for (int j = 0; j < 8; ++j)
        u[j] = (unsigned int)f2bf(v[2 * j]) | ((unsigned int)f2bf(v[2 * j + 1]) << 16);
    unsigned int* dst = (unsigned int*)&Wt[(size_t)nr * 64 + kc];
    *(uint4*)(dst)     = make_uint4(u[0], u[1], u[2], u[3]);
    *(uint4*)(dst + 4) = make_uint4(u[4], u[5], u[6], u[7]);
}

// ---------------------------------------------------------------------------
// Capsule layer 1. Grid (48 kl, 4 m-tiles), 256 thr.
// ---------------------------------------------------------------------------
__global__ __launch_bounds__(256) void caps_gemm1(
    const float* __restrict__ x, const float* __restrict__ C1,
    const unsigned short* __restrict__ W1t, const float* __restrict__ b1,
    unsigned short* __restrict__ xp)
{
    __shared__ __align__(16) unsigned short As[128 * 72];
    __shared__ __align__(16) unsigned short Bs[64 * 72];
    __shared__ float Csh[48];
    int kl = blockIdx.x;
    int bm = blockIdx.y * 128;
    int tid = threadIdx.x;
    int w = tid >> 6, lane = tid & 63, q = lane >> 4, r16 = lane & 15;
    int wm = (w >> 1) * 64, wn = (w & 1) * 32;

    if (tid < 48) Csh[tid] = C1[tid * 48 + kl];
    {
        const uint4* src = (const uint4*)(W1t + (size_t)kl * 4096);
        #pragma unroll
        for (int p = 0; p < 2; ++p) {
            int c = tid + p * 256;
            int row = c >> 3, cq = c & 7;
            *(uint4*)&Bs[row * 72 + cq * 8] = src[c];
        }
    }
    __syncthreads();

    int arow = tid >> 1, ah = (tid & 1) * 32;
    float accp[32];
    #pragma unroll
    for (int i = 0; i < 32; ++i) accp[i] = 0.f;
    const float* xrow = x + (size_t)(bm + arow) * 3072 + ah;
    for (int ij = 0; ij < 48; ++ij) {
        float c = Csh[ij];
        if (c != 0.f) {
            const float4* p4 = (const float4*)(xrow + ij * 64);
            #pragma unroll
            for (int cc = 0; cc < 8; ++cc) {
                float4 v = p4[cc];
                accp[cc * 4 + 0] = fmaf(c, v.x, accp[cc * 4 + 0]);
                accp[cc * 4 + 1] = fmaf(c, v.y, accp[cc * 4 + 1]);
                accp[cc * 4 + 2] = fmaf(c, v.z, accp[cc * 4 + 2]);
                accp[cc * 4 + 3] = fmaf(c, v.w, accp[cc * 4 + 3]);
            }
        }
    }
    {
        unsigned short* dst = &As[arow * 72 + ah];
        #pragma unroll
        for (int cc = 0; cc < 4; ++cc) {
            unsigned int u[4];
            #pragma unroll
            for (int j = 0; j < 4; ++j)
                u[j] = (unsigned int)f2bf(accp[cc * 8 + 2 * j]) |
                       ((unsigned int)f2bf(accp[cc * 8 + 2 * j + 1]) << 16);
            *(uint4*)&dst[cc * 8] = make_uint4(u[0], u[1], u[2], u[3]);
        }
    }
    __syncthreads();

    f32x4 acc[4][2];
    #pragma unroll
    for (int i = 0; i < 4; ++i)
        #pragma unroll
        for (int j = 0; j < 2; ++j) acc[i][j] = (f32x4)0.f;
    #pragma unroll
    for (int ks = 0; ks < 2; ++ks) {
        short8 a[4], b[2];
        #pragma unroll
        for (int mt = 0; mt < 4; ++mt)
            a[mt] = *(const short8*)&As[(wm + mt * 16 + r16) * 72 + ks * 32 + q * 8];
        #pragma unroll
        for (int nt = 0; nt < 2; ++nt)
            b[nt] = *(const short8*)&Bs[(wn + nt * 16 + r16) * 72 + ks * 32 + q * 8];
        #pragma unroll
        for (int mt = 0; mt < 4; ++mt)
            #pragma unroll
            for (int nt = 0; nt < 2; ++nt)
                acc[mt][nt] = __builtin_amdgcn_mfma_f32_16x16x32_bf16(a[mt], b[nt], acc[mt][nt], 0, 0, 0);
    }

    #pragma unroll
    for (int mt = 0; mt < 4; ++mt) {
        #pragma unroll
        for (int nt = 0; nt < 2; ++nt) {
            int n = wn + nt * 16 + r16;
            float bv = b1[kl * 64 + n];
            #pragma unroll
            for (int reg = 0; reg < 4; ++reg) {
                int row = bm + wm + mt * 16 + q * 4 + reg;
                xp[(size_t)row * 3072 + kl * 64 + n] = f2bf(fmaxf(acc[mt][nt][reg] + bv, 0.f));
            }
        }
    }
}

// ---------------------------------------------------------------------------
// Capsule layer 2 + skip + norms. Grid (40 kl, 4 m-tiles), 256 thr.
// ---------------------------------------------------------------------------
__global__ __launch_bounds__(256) void caps_gemm2(
    const unsigned short* __restrict__ xp, const float* __restrict__ Cs,
    const float* __restrict__ C2, const unsigned short* __restrict__ W2t,
    const float* __restrict__ b2, float* __restrict__ xsum,
    float* __restrict__ part8)
{
    __shared__ __align__(16) unsigned short As[128 * 72];
    __shared__ __align__(16) unsigned short Bs[64 * 72];
    __shared__ float C2sh[48], Cssh[48];
    int kl = blockIdx.x;
    int bm = blockIdx.y * 128;
    int tid = threadIdx.x;
    int w = tid >> 6, lane = tid & 63, q = lane >> 4, r16 = lane & 15;
    int wm = (w >> 1) * 64, wn = (w & 1) * 32;
    int half = w & 1;

    if (tid < 48) { C2sh[tid] = C2[tid * 40 + kl]; Cssh[tid] = Cs[tid * 40 + kl]; }
    {
        const uint4* src = (const uint4*)(W2t + (size_t)kl * 4096);
        #pragma unroll
        for (int p = 0; p < 2; ++p) {
            int c = tid + p * 256;
            int row = c >> 3, cq = c & 7;
            *(uint4*)&Bs[row * 72 + cq * 8] = src[c];
        }
    }
    __syncthreads();

    int arow = tid >> 1, ah = (tid & 1) * 32;
    float accp[32], skp[32];
    #pragma unroll
    for (int i = 0; i < 32; ++i) { accp[i] = 0.f; skp[i] = 0.f; }
    const unsigned short* xprow = xp + (size_t)(bm + arow) * 3072 + ah;
    for (int ij = 0; ij < 48; ++ij) {
        float c2 = C2sh[ij], cs = Cssh[ij];
        if (c2 != 0.f || cs != 0.f) {
            const uint4* p4 = (const uint4*)(xprow + ij * 64);
            #pragma unroll
            for (int cc = 0; cc < 4; ++cc) {
                uint4 v = p4[cc];
                unsigned int uu[4] = {v.x, v.y, v.z, v.w};
                #pragma unroll
                for (int j = 0; j < 4; ++j) {
                    float lo = bf2f(uu[j] & 0xffffu);
                    float hi = bf2f(uu[j] >> 16);
                    int idx = cc * 8 + 2 * j;
                    accp[idx]     = fmaf(c2, lo, accp[idx]);
                    accp[idx + 1] = fmaf(c2, hi, accp[idx + 1]);
                    skp[idx]      = fmaf(cs, lo, skp[idx]);
                    skp[idx + 1]  = fmaf(cs, hi, skp[idx + 1]);
                }
            }
        }
    }
    {
        unsigned short* dst = &As[arow * 72 + ah];
        #pragma unroll
        for (int cc = 0; cc < 4; ++cc) {
            unsigned int u[4];
            #pragma unroll
            for (int j = 0; j < 4; ++j)
                u[j] = (unsigned int)f2bf(accp[cc * 8 + 2 * j]) |
                       ((unsigned int)f2bf(accp[cc * 8 + 2 * j + 1]) << 16);
            *(uint4*)&dst[cc * 8] = make_uint4(u[0], u[1], u[2], u[3]);
        }
        float* sx = xsum + (size_t)(bm + arow) * 2560 + kl * 64 + ah;
        #pragma unroll
        for (int cc = 0; cc < 8; ++cc)
            *(float4*)&sx[cc * 4] = make_float4(skp[cc*4], skp[cc*4+1], skp[cc*4+2], skp[cc*4+3]);
    }
    __syncthreads();

    f32x4 acc[4][2];
    #pragma unroll
    for (int i = 0; i < 4; ++i)
        #pragma unroll
        for (int j = 0; j < 2; ++j) acc[i][j] = (f32x4)0.f;
    #pragma unroll
    for (int ks = 0; ks < 2; ++ks) {
        short8 a[4], b[2];
        #pragma unroll
        for (int mt = 0; mt < 4; ++mt)
            a[mt] = *(const short8*)&As[(wm + mt * 16 + r16) * 72 + ks * 32 + q * 8];
        #pragma unroll
        for (int nt = 0; nt < 2; ++nt)
            b[nt] = *(const short8*)&Bs[(wn + nt * 16 + r16) * 72 + ks * 32 + q * 8];
        #pragma unroll
        for (int mt = 0; mt < 4; ++mt)
            #pragma unroll
            for (int nt = 0; nt < 2; ++nt)
                acc[mt][nt] = __builtin_amdgcn_mfma_f32_16x16x32_bf16(a[mt], b[nt], acc[mt][nt], 0, 0, 0);
    }

    #pragma unroll
    for (int mt = 0; mt < 4; ++mt) {
        float sreg[4] = {0.f, 0.f, 0.f, 0.f};
        #pragma unroll
        for (int nt = 0; nt < 2; ++nt) {
            int n = wn + nt * 16 + r16;
            float bv = b2[kl * 64 + n];
            #pragma unroll
            for (int reg = 0; reg < 4; ++reg) {
                int lr = wm + mt * 16 + q * 4 + reg;
                size_t xi = (size_t)(bm + lr) * 2560 + kl * 64 + n;
                float v = xsum[xi] + fmaxf(acc[mt][nt][reg] + bv, 0.f);
                xsum[xi] = v;
                sreg[reg] += v * v;
            }
        }
        #pragma unroll
        for (int reg = 0; reg < 4; ++reg) {
            float s = sreg[reg];
            s += __shfl_xor(s, 1); s += __shfl_xor(s, 2);
            s += __shfl_xor(s, 4); s += __shfl_xor(s, 8);
            if (r16 == 0) {
                int row = bm + wm + mt * 16 + q * 4 + reg;
                part8[(size_t)row * 80 + kl * 2 + half] = s;
            }
        }
    }
}

// ---------------------------------------------------------------------------
// Norm-argmax; writes only the active 256-capsule slice of xrec (bf16).
// ---------------------------------------------------------------------------
__global__ __launch_bounds__(256) void mask_kernel(
    const float* __restrict__ xs, const float* __restrict__ part8,
    unsigned short* __restrict__ xrec, int* __restrict__ active)
{
    int b = blockIdx.x;
    int tid = threadIdx.x;
    __shared__ float norms[10];
    __shared__ int act_sh;
    if (tid < 10) {
        float s = 0.f;
        #pragma unroll
        for (int j = 0; j < 8; ++j) s += part8[(size_t)b * 80 + tid * 8 + j];
        norms[tid] = s;
    }
    __syncthreads();
    if (tid == 0) {
        int best = 0; float bn = -1.f;
        #pragma unroll
        for (int k = 0; k < 10; ++k)
            if (norms[k] > bn) { bn = norms[k]; best = k; }
        act_sh = best;
        active[b] = best;
    }
    __syncthreads();
    int act = act_sh;
    int idx = act * 256 + tid;
    xrec[(size_t)b * LD_XREC + idx] = f2bf(xs[(size_t)b * 2560 + idx]);
}

// ---------------------------------------------------------------------------
// Bucket rows by active capsule: perm + slot table (<=18 slots).
// ---------------------------------------------------------------------------
__global__ __launch_bounds__(512) void bucket_kernel(
    const int* __restrict__ active, int* __restrict__ perm,
    int4* __restrict__ slots)
{
    __shared__ int cnt[10], pos[10];
    int tid = threadIdx.x;
    if (tid < 10) cnt[tid] = 0;
    __syncthreads();
    int a = active[tid];
    atomicAdd(&cnt[a], 1);
    __syncthreads();
    if (tid == 0) {
        int o = 0, s = 0;
        for (int g = 0; g < 10; ++g) {
            pos[g] = o;
            int mg = cnt[g];
            for (int t0 = 0; t0 < mg; t0 += 64)
                slots[s++] = make_int4(g, o + t0, min(64, mg - t0), 0);
            o += mg;
        }
        for (; s < 18; ++s) slots[s] = make_int4(0, 0, 0, 0);
    }
    __syncthreads();
    int r = atomicAdd(&pos[a], 1);
    perm[r] = tid;
}

// ---------------------------------------------------------------------------
// Grouped MLP layer-1 GEMM (64m x 128n, K=256), B from Wr1 f32 converted in
// staging, swizzled LDS; A via GLD16 with sigma pre-swizzle.
// ---------------------------------------------------------------------------
__global__ __launch_bounds__(256) void gemm_l1(
    const unsigned short* __restrict__ xrec, const int* __restrict__ perm,
    const int4* __restrict__ slots, const float* __restrict__ Wr1,
    const float* __restrict__ br1, unsigned short* __restrict__ h1)
{
    __shared__ __align__(16) unsigned short As[2][64 * 32];
    __shared__ __align__(16) unsigned short Bs[2][128 * 40];
    __shared__ int rows[64];

    int4 s = slots[blockIdx.y];
    if (s.z == 0) return;
    int g = s.x, mstart = s.y, mval = s.z;
    int bn = blockIdx.x * 128;
    int tid = threadIdx.x;

    if (tid < 64) rows[tid] = perm[mstart + min(tid, mval - 1)];
    __syncthreads();

    int w = tid >> 6, lane = tid & 63;
    int wm = (w >> 1) * 32, wn = (w & 1) * 64;
    int q = lane >> 4, r16 = lane & 15;
    int srow = tid >> 2;
    int akq = (tid & 3) ^ ((srow >> 1) & 3);   // sigma pre-swizzle

    f32x4 acc[2][4];
    #pragma unroll
    for (int i = 0; i < 2; ++i)
        #pragma unroll
        for (int j = 0; j < 4; ++j) acc[i][j] = (f32x4)0.f;

    int arow = rows[srow];
    const unsigned short* ga = xrec + (size_t)arow * LD_XREC + g * 256 + akq * 8;
    int kbase = g * 256;

    BReg br;
    loadB(br, Wr1, 5000, 2560, 5000, kbase, bn, tid);
    GLD16(ga, &As[0][tid * 8]);
    writeB(br, Bs[0], tid);
    __syncthreads();

    int cur = 0;
    for (int kk = 32; kk <= 256; kk += 32) {
        bool more = kk < 256;
        if (more) {
            GLD16(ga + kk, &As[cur ^ 1][tid * 8]);
            loadB(br, Wr1, 5000, 2560, 5000, kbase + kk, bn, tid);
        }
        short8 b[4];
        #pragma unroll
        for (int nt = 0; nt < 4; ++nt)
            b[nt] = readB(Bs[cur], wn + nt * 16 + r16, q);
        #pragma unroll
        for (int mt = 0; mt < 2; ++mt) {
            short8 a = readA(As[cur], wm + mt * 16 + r16, q);
            #pragma unroll
            for (int nt = 0; nt < 4; ++nt)
                acc[mt][nt] = __builtin_amdgcn_mfma_f32_16x16x32_bf16(a, b[nt], acc[mt][nt], 0, 0, 0);
        }
        if (more) writeB(br, Bs[cur ^ 1], tid);
        __syncthreads();
        cur ^= 1;
    }

    #pragma unroll
    for (int mt = 0; mt < 2; ++mt) {
        #pragma unroll
        for (int nt = 0; nt < 4; ++nt) {
            int n = bn + wn + nt * 16 + r16;
            float bv = (n < 5000) ? br1[n] : 0.f;
            #pragma unroll
            for (int reg = 0; reg < 4; ++reg) {
                int lm = wm + mt * 16 + q * 4 + reg;
                if (lm < mval)
                    h1[(size_t)(mstart + lm) * LD_H1 + n] =
                        f2bf(fmaxf(acc[mt][nt][reg] + bv, 0.f));
            }
        }
    }
}

// ---------------------------------------------------------------------------
// Big-tile split-K GEMM: BM=256, BN=128, BK=32, 256 thr (4 waves 2x2, each
// wave 128m x 64n = 8x4 frags). A bf16 GLD16 (sigma-swizzled source),
// B f32 [K][N] converted in staging. 1-D grid, XCD-pair decode:
//   xcd = bid&7; r=bid>>3; m=r&1; r2=r>>1; z=r2&7; bhi=r2>>3;
//   bn=(xcd+8*bhi)*128; -> m-pair for same (bn,z) lands on same XCD.
// 2-deep B register prefetch, 2-step-unrolled (static regs).
// ---------------------------------------------------------------------------
__global__ __launch_bounds__(256, 2) void gemm_big(
    const unsigned short* __restrict__ A, int ldA,
    const float* __restrict__ B, int ldB, int Kr, int Nr,
    float* __restrict__ P, int ldP, int kper)
{
    __shared__ __align__(16) unsigned short As[2][256 * 32];
    __shared__ __align__(16) unsigned short Bs[2][128 * 40];

    int tid = threadIdx.x;
    int bid = blockIdx.x;
    int xcd = bid & 7;
    int r   = bid >> 3;
    int mi  = r & 1;
    int r2  = r >> 1;
    int z   = r2 & 7;
    int bhi = r2 >> 3;
    int bn = (xcd + 8 * bhi) * 128;
    int bm = mi * 256;
    int kz = z * kper;

    int w = tid >> 6, lane = tid & 63;
    int wm = (w >> 1) * 128, wn = (w & 1) * 64;
    int q = lane >> 4, r16 = lane & 15;

    f32x4 acc[8][4];
    #pragma unroll
    for (int i = 0; i < 8; ++i)
        #pragma unroll
        for (int j = 0; j < 4; ++j) acc[i][j] = (f32x4)0.f;

    // A staging: 4 GLD16/thread; granule g=tid+p*256 -> row=g>>2, k8=g&3,
    // source k-granule = k8 ^ sigma(row)
    const unsigned short* ga[4];
    #pragma unroll
    for (int p = 0; p < 4; ++p) {
        int row = (tid >> 2) + p * 64;
        int kq8 = (tid & 3) ^ ((row >> 1) & 3);
        ga[p] = A + (size_t)(bm + row) * ldA + kz + kq8 * 8;
    }

    int nst = kper / 32;     // even (20 or 16)
    BReg brE, brO;

    // prologue: Bs[0]=B(0), brO=B(1), A(0)->As[0]
    loadB(brE, B, ldB, Kr, Nr, kz, bn, tid);
    loadB(brO, B, ldB, Kr, Nr, kz + 32, bn, tid);
    #pragma unroll
    for (int p = 0; p < 4; ++p) GLD16(ga[p], &As[0][(tid + p * 256) * 8]);
    writeB(brE, Bs[0], tid);
    __syncthreads();

    #define COMPUTE(BUF)                                                      \
    {                                                                         \
        short8 b0 = readB(Bs[BUF], wn + r16,      q);                         \
        short8 b1 = readB(Bs[BUF], wn + 16 + r16, q);                         \
        short8 b2 = readB(Bs[BUF], wn + 32 + r16, q);                         \
        short8 b3 = readB(Bs[BUF], wn + 48 + r16, q);                         \
        _Pragma("unroll")                                                     \
        for (int mt = 0; mt < 8; ++mt) {                                      \
            short8 a = readA(As[BUF], wm + mt * 16 + r16, q);                 \
            acc[mt][0] = __builtin_amdgcn_mfma_f32_16x16x32_bf16(a, b0, acc[mt][0], 0, 0, 0); \
            acc[mt][1] = __builtin_amdgcn_mfma_f32_16x16x32_bf16(a, b1, acc[mt][1], 0, 0, 0); \
            acc[mt][2] = __builtin_amdgcn_mfma_f32_16x16x32_bf16(a, b2, acc[mt][2], 0, 0, 0); \
            acc[mt][3] = __builtin_amdgcn_mfma_f32_16x16x32_bf16(a, b3, acc[mt][3], 0, 0, 0); \
        }                                                                     \
    }

    for (int s = 0; s < nst; s += 2) {
        // even step s: compute buf0; brO holds B(s+1); brE free
        if (s + 2 < nst) loadB(brE, B, ldB, Kr, Nr, kz + (s + 2) * 32, bn, tid);
        if (s + 1 < nst) {
            #pragma unroll
            for (int p = 0; p < 4; ++p)
                GLD16(ga[p] + (s + 1) * 32, &As[1][(tid + p * 256) * 8]);
        }
        COMPUTE(0);
        if (s + 1 < nst) writeB(brO, Bs[1], tid);
        __syncthreads();
        // odd step s+1: compute buf1; brE holds B(s+2); brO free
        if (s + 3 < nst) loadB(brO, B, ldB, Kr, Nr, kz + (s + 3) * 32, bn, tid);
        if (s + 2 < nst) {
            #pragma unroll
            for (int p = 0; p < 4; ++p)
                GLD16(ga[p] + (s + 2) * 32, &As[0][(tid + p * 256) * 8]);
        }
        COMPUTE(1);
        if (s + 2 < nst) writeB(brE, Bs[0], tid);
        __syncthreads();
    }
    #undef COMPUTE

    float* Pz = P + (size_t)z * 512 * ldP;
    #pragma unroll
    for (int mt = 0; mt < 8; ++mt) {
        #pragma unroll
        for (int nt = 0; nt < 4; ++nt) {
            int cn = bn + wn + nt * 16 + r16;
            #pragma unroll
            for (int reg = 0; reg < 4; ++reg) {
                int cm = bm + wm + mt * 16 + q * 4 + reg;
                Pz[(size_t)cm * ldP + cn] = acc[mt][nt][reg];
            }
        }
    }
}

// ---------------------------------------------------------------------------
// Combine 8 split-K partials + bias + act.
// MODE 0: relu->bf16 (stride ldO). MODE 1: sigmoid->f32, un-permute rows.
// ---------------------------------------------------------------------------
template<int MODE>
__global__ __launch_bounds__(256) void combine_kernel(
    const float* __restrict__ P, int ldP, const float* __restrict__ bias,
    void* __restrict__ out, int ldO, int Np, int N_real,
    const int* __restrict__ perm)
{
    int gid = blockIdx.x * 256 + threadIdx.x;
    int n0 = (gid * 4) % Np;
    int m  = (gid * 4) / Np;
    size_t MN = (size_t)512 * ldP;
    const float* p = P + (size_t)m * ldP + n0;
    f32x4 s = *(const f32x4*)p;
    #pragma unroll
    for (int zz = 1; zz < NZ; ++zz)
        s += *(const f32x4*)(p + (size_t)zz * MN);
    f32x4 bv = (n0 < N_real) ? *(const f32x4*)(bias + n0) : (f32x4)0.f;
    s += bv;
    if (MODE == 0) {
        unsigned int lo = (unsigned int)f2bf(fmaxf(s[0], 0.f)) | ((unsigned int)f2bf(fmaxf(s[1], 0.f)) << 16);
        unsigned int hi = (unsigned int)f2bf(fmaxf(s[2], 0.f)) | ((unsigned int)f2bf(fmaxf(s[3], 0.f)) << 16);
        *(uint2*)((unsigned short*)out + (size_t)m * ldO + n0) = make_uint2(lo, hi);
    } else {
        int row = perm[m];
        f32x4 v;
        v[0] = 1.f / (1.f + expf(-s[0]));
        v[1] = 1.f / (1.f + expf(-s[1]));
        v[2] = 1.f / (1.f + expf(-s[2]));
        v[3] = 1.f / (1.f + expf(-s[3]));
        *(f32x4*)((float*)out + (size_t)row * ldO + n0) = v;
    }
}

extern "C" void kernel_launch(void* const* d_in, const int* in_sizes, int n_in,
                              void* d_out, int out_size, void* d_ws, size_t ws_size,
                              hipStream_t stream) {
    const float* x   = (const float*)d_in[0];
    const float* C1  = (const float*)d_in[1];
    const float* W1  = (const float*)d_in[2];
    const float* b1  = (const float*)d_in[3];
    const float* Cs  = (const float*)d_in[4];
    const float* C2  = (const float*)d_in[5];
    const float* W2  = (const float*)d_in[6];
    const float* b2  = (const float*)d_in[7];
    const float* Wr1 = (const float*)d_in[8];
    const float* br1 = (const float*)d_in[9];
    const float* Wr2 = (const float*)d_in[10];
    const float* br2 = (const float*)d_in[11];
    const float* Wr3 = (const float*)d_in[12];
    const float* br3 = (const float*)d_in[13];

    float* out = (float*)d_out;
    float* out0     = out;              // (512,3072) f32 sigmoid output
    float* xsum_out = out + OUT0_SZ;    // (512,2560) f32 x_sum

    // workspace layout (bytes)
    char* base = (char*)d_ws;
    unsigned short* xrec = (unsigned short*)(base);               // 512*2576*2 = 2,637,824
    unsigned short* h1   = (unsigned short*)(base +  2637824);    // 512*5136*2 = 5,259,264
    unsigned short* h2   = (unsigned short*)(base +  7897088);    // 512*4112*2 = 4,210,688
    unsigned short* xp   = (unsigned short*)(base + 12107776);    // 512*3072*2 = 3,145,728
    unsigned short* W1t  = (unsigned short*)(base + 15253504);    //    393,216
    unsigned short* W2t  = (unsigned short*)(base + 15646720);    //    327,680
    float*          part8= (float*)(base + 15974400);             //    163,840
    int*  active = (int*)(base + 16138240);                       //      2,048
    int*  perm   = active + 512;                                  //      2,048
    int4* slots  = (int4*)(perm + 512);                           //        288
    float*          Pbuf = (float*)(base + 16144384);             // 8*512*4224*4 = 69,206,016
    // total ~85.4 MB

    // capsule weight transposes (tiny)
    conv_small<<<88, 256, 0, stream>>>(W1, W1t, W2, W2t);

    // capsule path
    caps_gemm1<<<dim3(48, 4), 256, 0, stream>>>(x, C1, W1t, b1, xp);
    caps_gemm2<<<dim3(40, 4), 256, 0, stream>>>(xp, Cs, C2, W2t, b2, xsum_out, part8);
    mask_kernel<<<BATCH, 256, 0, stream>>>(xsum_out, part8, xrec, active);
    bucket_kernel<<<1, 512, 0, stream>>>(active, perm, slots);

    // MLP layer 1 (grouped, K=256, B from Wr1 f32) -> h1 (permuted rows)
    gemm_l1<<<dim3(5120 / 128, 18), 256, 0, stream>>>(xrec, perm, slots, Wr1, br1, h1);

    // MLP layer 2: (512,5120 bf16) x Wr2 f32 [5000][4000] -> h2
    // grid = 8 xcd * 2 m * 8 z * nbhi(4) = 512; kper = 5120/8 = 640
    gemm_big<<<512, 256, 0, stream>>>(h1, LD_H1, Wr2, 4000, 5000, 4000, Pbuf, LDP2, 640);
    combine_kernel<0><<<512 * 4096 / 1024, 256, 0, stream>>>(
        Pbuf, LDP2, br2, h2, LD_H2, 4096, 4000, nullptr);

    // MLP layer 3: (512,4096 bf16) x Wr3 f32 [4000][3072] -> out0 (un-permuted)
    // grid = 8 * 2 * 8 * nbhi(3) = 384; kper = 4096/8 = 512 (A cols 4000..4095 = 0)
    gemm_big<<<384, 256, 0, stream>>>(h2, LD_H2, Wr3, 3072, 4000, 3072, Pbuf, LDP3, 512);
    combine_kernel<1><<<512 * 3072 / 1024, 256, 0, stream>>>(
        Pbuf, LDP3, br3, out0, 3072, 3072, 3072, perm);
}